// Round 1
// baseline (636.752 us; speedup 1.0000x reference)
//
#include <hip/hip_runtime.h>
#include <hip/hip_bf16.h>
#include <math.h>

// Problem constants
#define Bx 8
#define Cc 256
#define Nn 4096      // 64*64
#define TMPc 512
#define HEADSc 8
#define HIDc 64

union F4 { float4 v; float f[4]; };

__device__ __forceinline__ float gelu_exact(float x) {
  return x * 0.5f * (1.0f + erff(x * 0.70710678118654752f));
}

// ---------------- depthwise 3x3, padding SAME ----------------
__global__ __launch_bounds__(256) void dwconv_k(const float* __restrict__ fmap,
                                                const float* __restrict__ Wdw,
                                                float* __restrict__ dw) {
  __shared__ __align__(16) float sp[4096];
  int c = blockIdx.x, z = blockIdx.y;
  const float* src = fmap + ((size_t)z * Cc + c) * 4096;
  float w[9];
#pragma unroll
  for (int i = 0; i < 9; ++i) w[i] = Wdw[c * 9 + i];
  int t = threadIdx.x;
#pragma unroll
  for (int i = 0; i < 4; ++i)
    *(float4*)&sp[i * 1024 + t * 4] = *(const float4*)&src[i * 1024 + t * 4];
  __syncthreads();
  float* dst = dw + ((size_t)z * Cc + c) * 4096;
  int x = t & 63;
#pragma unroll
  for (int i = 0; i < 16; ++i) {
    int p = i * 256 + t;
    int y = p >> 6;
    float acc = 0.0f;
#pragma unroll
    for (int dy = -1; dy <= 1; ++dy) {
      int yy = y + dy;
      if ((unsigned)yy < 64u) {
#pragma unroll
        for (int dx = -1; dx <= 1; ++dx) {
          int xx = x + dx;
          if ((unsigned)xx < 64u) acc += sp[yy * 64 + xx] * w[(dy + 1) * 3 + (dx + 1)];
        }
      }
    }
    dst[p] = acc;
  }
}

// ---------------- f32 GEMM: Y[z][m][n] = sum_k W[m][k] * X[z][k][n] (+bias) ----
// 128x128 tile, KT=16, 256 threads, 8x8 microtile (split 4+4 rows/cols).
__global__ __launch_bounds__(256) void gemm_k(const float* __restrict__ W,
                                              const float* __restrict__ X,
                                              float* __restrict__ Y,
                                              const float* __restrict__ bias,
                                              int K, long xs, long ys) {
  __shared__ __align__(16) float As[16][128];  // [k][m]
  __shared__ __align__(16) float Bs[16][128];  // [k][n]
  int t = threadIdx.x;
  int tileN = blockIdx.x * 128;
  int tileM = blockIdx.y * 128;
  const float* Xz = X + (size_t)blockIdx.z * xs;
  float* Yz = Y + (size_t)blockIdx.z * ys;
  float acc[8][8] = {};
  int mw = t >> 2, kc = t & 3;   // W-tile load mapping
  int xc = t & 31, xr = t >> 5;  // X-tile load mapping
  int ty = t >> 4, tx = t & 15;  // compute mapping

  for (int k0 = 0; k0 < K; k0 += 16) {
    F4 w0, w1, x0, x1;
    w0.v = *(const float4*)&W[(size_t)(tileM + mw) * K + k0 + kc * 4];
    w1.v = *(const float4*)&W[(size_t)(tileM + mw + 64) * K + k0 + kc * 4];
    x0.v = *(const float4*)&Xz[(size_t)(k0 + xr) * Nn + tileN + xc * 4];
    x1.v = *(const float4*)&Xz[(size_t)(k0 + xr + 8) * Nn + tileN + xc * 4];
    __syncthreads();
#pragma unroll
    for (int j = 0; j < 4; ++j) {
      As[kc * 4 + j][mw] = w0.f[j];
      As[kc * 4 + j][mw + 64] = w1.f[j];
    }
    *(float4*)&Bs[xr][xc * 4] = x0.v;
    *(float4*)&Bs[xr + 8][xc * 4] = x1.v;
    __syncthreads();
#pragma unroll
    for (int kk = 0; kk < 16; ++kk) {
      float a[8], b[8];
      F4 u;
      u.v = *(const float4*)&As[kk][ty * 4];
#pragma unroll
      for (int i = 0; i < 4; ++i) a[i] = u.f[i];
      u.v = *(const float4*)&As[kk][64 + ty * 4];
#pragma unroll
      for (int i = 0; i < 4; ++i) a[4 + i] = u.f[i];
      u.v = *(const float4*)&Bs[kk][tx * 4];
#pragma unroll
      for (int i = 0; i < 4; ++i) b[i] = u.f[i];
      u.v = *(const float4*)&Bs[kk][64 + tx * 4];
#pragma unroll
      for (int i = 0; i < 4; ++i) b[4 + i] = u.f[i];
#pragma unroll
      for (int i = 0; i < 8; ++i)
#pragma unroll
        for (int j = 0; j < 8; ++j) acc[i][j] += a[i] * b[j];
    }
  }
#pragma unroll
  for (int i = 0; i < 8; ++i) {
    int m = tileM + ((i < 4) ? (ty * 4 + i) : (64 + ty * 4 + (i - 4)));
    float bv = bias ? bias[m] : 0.0f;
    F4 o0, o1;
#pragma unroll
    for (int j = 0; j < 4; ++j) { o0.f[j] = acc[i][j] + bv; o1.f[j] = acc[i][4 + j] + bv; }
    *(float4*)&Yz[(size_t)m * Nn + tileN + tx * 4] = o0.v;
    *(float4*)&Yz[(size_t)m * Nn + tileN + 64 + tx * 4] = o1.v;
  }
}

// ---------------- q softmax over feature dim d (stride Nn), * 1/sqrt(64) ------
__global__ __launch_bounds__(256) void qsm_k(float* __restrict__ q) {
  int xy = blockIdx.x * 256 + threadIdx.x;
  int h = blockIdx.y & 7, z = blockIdx.y >> 3;
  size_t base = ((size_t)z * TMPc + h * 64) * Nn + xy;
  float v[64];
  float m = -1e30f;
#pragma unroll
  for (int d = 0; d < 64; ++d) { v[d] = q[base + (size_t)d * Nn]; m = fmaxf(m, v[d]); }
  float s = 0.0f;
#pragma unroll
  for (int d = 0; d < 64; ++d) { v[d] = __expf(v[d] - m); s += v[d]; }
  float inv = 0.125f / s;
#pragma unroll
  for (int d = 0; d < 64; ++d) q[base + (size_t)d * Nn] = v[d] * inv;
}

// ---------------- k softmax over token dim n (contiguous row of 4096) --------
__global__ __launch_bounds__(256) void ksm_k(float* __restrict__ kv) {
  int ch = blockIdx.x, z = blockIdx.y;
  float* row = kv + ((size_t)z * 2 * TMPc + ch) * Nn;
  int t = threadIdx.x;
  float v[16];
  float m = -1e30f;
#pragma unroll
  for (int p = 0; p < 4; ++p) {
    F4 f; f.v = *(const float4*)&row[p * 1024 + t * 4];
#pragma unroll
    for (int j = 0; j < 4; ++j) { v[p * 4 + j] = f.f[j]; m = fmaxf(m, f.f[j]); }
  }
#pragma unroll
  for (int off = 32; off >= 1; off >>= 1) m = fmaxf(m, __shfl_xor(m, off, 64));
  __shared__ float red[8];
  int w = t >> 6;
  if ((t & 63) == 0) red[w] = m;
  __syncthreads();
  m = fmaxf(fmaxf(red[0], red[1]), fmaxf(red[2], red[3]));
  float s = 0.0f;
#pragma unroll
  for (int i = 0; i < 16; ++i) { v[i] = __expf(v[i] - m); s += v[i]; }
#pragma unroll
  for (int off = 32; off >= 1; off >>= 1) s += __shfl_xor(s, off, 64);
  if ((t & 63) == 0) red[4 + w] = s;
  __syncthreads();
  s = red[4] + red[5] + red[6] + red[7];
  float inv = 1.0f / s;
#pragma unroll
  for (int p = 0; p < 4; ++p) {
    F4 f;
#pragma unroll
    for (int j = 0; j < 4; ++j) f.f[j] = v[p * 4 + j] * inv;
    *(float4*)&row[p * 1024 + t * 4] = f.v;
  }
}

// ---------------- ctx[d][e] = sum_n k[d][n]*v[e][n], n-split + atomics -------
__global__ __launch_bounds__(256) void ctx_k(const float* __restrict__ kv,
                                             float* __restrict__ ctx) {
  __shared__ __align__(16) float Ks[16][64];
  __shared__ __align__(16) float Vs[16][64];
  int h = blockIdx.y & 7, z = blockIdx.y >> 3;
  int n0 = blockIdx.x * 256;
  const float* kb = kv + ((size_t)z * 2 * TMPc + h * 64) * Nn + n0;
  const float* vb = kv + ((size_t)z * 2 * TMPc + TMPc + h * 64) * Nn + n0;
  int t = threadIdx.x;
  int d = t >> 2, rr = (t & 3) * 4;
  int ty = t >> 4, tx = t & 15;
  float acc[4][4] = {};
  for (int kt = 0; kt < 256; kt += 16) {
    F4 kf, vf;
    kf.v = *(const float4*)&kb[(size_t)d * Nn + kt + rr];
    vf.v = *(const float4*)&vb[(size_t)d * Nn + kt + rr];
    __syncthreads();
#pragma unroll
    for (int j = 0; j < 4; ++j) { Ks[rr + j][d] = kf.f[j]; Vs[rr + j][d] = vf.f[j]; }
    __syncthreads();
#pragma unroll
    for (int r = 0; r < 16; ++r) {
      float a[4], b[4];
      F4 u;
      u.v = *(const float4*)&Ks[r][ty * 4];
#pragma unroll
      for (int i = 0; i < 4; ++i) a[i] = u.f[i];
      u.v = *(const float4*)&Vs[r][tx * 4];
#pragma unroll
      for (int i = 0; i < 4; ++i) b[i] = u.f[i];
#pragma unroll
      for (int i = 0; i < 4; ++i)
#pragma unroll
        for (int j = 0; j < 4; ++j) acc[i][j] += a[i] * b[j];
    }
  }
  float* cb = ctx + (size_t)(z * 8 + h) * 4096;
#pragma unroll
  for (int i = 0; i < 4; ++i)
#pragma unroll
    for (int j = 0; j < 4; ++j)
      atomicAdd(&cb[(ty * 4 + i) * 64 + tx * 4 + j], acc[i][j]);
}

// ---------------- out[e][n] = gelu( sum_d ctx[d][e] * q[d][n] ) --------------
__global__ __launch_bounds__(256) void attn_k(const float* __restrict__ q,
                                              const float* __restrict__ ctx,
                                              float* __restrict__ gout) {
  __shared__ __align__(16) float cs[64][64];   // [d][e]
  __shared__ __align__(16) float Qs[16][256];  // [d][n]
  int h = blockIdx.y & 7, z = blockIdx.y >> 3;
  int n0 = blockIdx.x * 256;
  int t = threadIdx.x;
  const float* cbase = ctx + (size_t)(z * 8 + h) * 4096;
#pragma unroll
  for (int i = 0; i < 4; ++i)
    *(float4*)&((float*)cs)[i * 1024 + t * 4] = *(const float4*)&cbase[i * 1024 + t * 4];
  const float* qb = q + ((size_t)z * TMPc + h * 64) * Nn + n0;
  int c4 = (t & 63) * 4, r0 = t >> 6;
  int ty = t >> 5, tx = t & 31;
  float acc[8][8] = {};
  for (int kt = 0; kt < 64; kt += 16) {
    F4 f0, f1, f2, f3;
    f0.v = *(const float4*)&qb[(size_t)(kt + r0) * Nn + c4];
    f1.v = *(const float4*)&qb[(size_t)(kt + r0 + 4) * Nn + c4];
    f2.v = *(const float4*)&qb[(size_t)(kt + r0 + 8) * Nn + c4];
    f3.v = *(const float4*)&qb[(size_t)(kt + r0 + 12) * Nn + c4];
    __syncthreads();
    *(float4*)&Qs[r0][c4] = f0.v;
    *(float4*)&Qs[r0 + 4][c4] = f1.v;
    *(float4*)&Qs[r0 + 8][c4] = f2.v;
    *(float4*)&Qs[r0 + 12][c4] = f3.v;
    __syncthreads();
#pragma unroll
    for (int kk = 0; kk < 16; ++kk) {
      float ce[8], qv[8];
      F4 u;
      u.v = *(const float4*)&cs[kt + kk][ty * 8];
#pragma unroll
      for (int i = 0; i < 4; ++i) ce[i] = u.f[i];
      u.v = *(const float4*)&cs[kt + kk][ty * 8 + 4];
#pragma unroll
      for (int i = 0; i < 4; ++i) ce[4 + i] = u.f[i];
      u.v = *(const float4*)&Qs[kk][tx * 4];
#pragma unroll
      for (int i = 0; i < 4; ++i) qv[i] = u.f[i];
      u.v = *(const float4*)&Qs[kk][128 + tx * 4];
#pragma unroll
      for (int i = 0; i < 4; ++i) qv[4 + i] = u.f[i];
#pragma unroll
      for (int i = 0; i < 8; ++i)
#pragma unroll
        for (int j = 0; j < 8; ++j) acc[i][j] += ce[i] * qv[j];
    }
  }
#pragma unroll
  for (int i = 0; i < 8; ++i) {
    int e = ty * 8 + i;
    float* dst = gout + ((size_t)z * TMPc + h * 64 + e) * Nn + n0;
    F4 o0, o1;
#pragma unroll
    for (int j = 0; j < 4; ++j) {
      o0.f[j] = gelu_exact(acc[i][j]);
      o1.f[j] = gelu_exact(acc[i][4 + j]);
    }
    *(float4*)&dst[tx * 4] = o0.v;
    *(float4*)&dst[128 + tx * 4] = o1.v;
  }
}

extern "C" void kernel_launch(void* const* d_in, const int* in_sizes, int n_in,
                              void* d_out, int out_size, void* d_ws, size_t ws_size,
                              hipStream_t stream) {
  (void)in_sizes; (void)n_in; (void)out_size;
  const float* fmap = (const float*)d_in[0];
  const float* Wq   = (const float*)d_in[1];
  const float* Wdw  = (const float*)d_in[2];
  const float* Wkv  = (const float*)d_in[3];
  const float* Wout = (const float*)d_in[4];
  const float* bout = (const float*)d_in[5];
  float* out = (float*)d_out;

  // per-batch f32 workspace: dw + q + kv + gout + ctx
  size_t perB = (size_t)Cc * Nn + (size_t)TMPc * Nn + (size_t)2 * TMPc * Nn +
                (size_t)TMPc * Nn + (size_t)HEADSc * HIDc * HIDc;
  int bc = Bx;
  while (bc > 1 && perB * (size_t)bc * sizeof(float) > ws_size) bc >>= 1;

  float* wsf = (float*)d_ws;
  for (int b0 = 0; b0 < Bx; b0 += bc) {
    float* dwb   = wsf;
    float* qb    = dwb + (size_t)bc * Cc * Nn;
    float* kvb   = qb + (size_t)bc * TMPc * Nn;
    float* goutb = kvb + (size_t)bc * 2 * TMPc * Nn;
    float* ctxb  = goutb + (size_t)bc * TMPc * Nn;
    const float* fchunk = fmap + (size_t)b0 * Cc * Nn;

    dwconv_k<<<dim3(Cc, bc), 256, 0, stream>>>(fchunk, Wdw, dwb);
    gemm_k<<<dim3(32, TMPc / 128, bc), 256, 0, stream>>>(
        Wq, fchunk, qb, nullptr, Cc, (long)Cc * Nn, (long)TMPc * Nn);
    gemm_k<<<dim3(32, 2 * TMPc / 128, bc), 256, 0, stream>>>(
        Wkv, dwb, kvb, nullptr, Cc, (long)Cc * Nn, (long)2 * TMPc * Nn);
    qsm_k<<<dim3(16, bc * 8), 256, 0, stream>>>(qb);
    ksm_k<<<dim3(TMPc, bc), 256, 0, stream>>>(kvb);
    hipMemsetAsync(ctxb, 0, (size_t)bc * HEADSc * HIDc * HIDc * sizeof(float), stream);
    ctx_k<<<dim3(16, bc * 8), 256, 0, stream>>>(kvb, ctxb);
    attn_k<<<dim3(16, bc * 8), 256, 0, stream>>>(qb, ctxb, goutb);
    gemm_k<<<dim3(32, Cc / 128, bc), 256, 0, stream>>>(
        Wout, goutb, out + (size_t)b0 * Cc * Nn, bout, TMPc, (long)TMPc * Nn, (long)Cc * Nn);
  }
}

// Round 2
// 184.979 us; speedup vs baseline: 3.4423x; 3.4423x over previous
//
#include <hip/hip_runtime.h>
#include <hip/hip_bf16.h>
#include <math.h>

#define Bx 8
#define Cc 256
#define Nn 4096
#define TMPc 512

typedef unsigned short ushort;
typedef unsigned int uint;
typedef __attribute__((ext_vector_type(8))) short bf16x8;
typedef __attribute__((ext_vector_type(4))) float f32x4;

union F4 { float4 v; float f[4]; };

__device__ __forceinline__ float gelu_exact(float x) {
  return x * 0.5f * (1.0f + erff(x * 0.70710678118654752f));
}
__device__ __forceinline__ ushort f2bf(float x) {
  uint u = __float_as_uint(x);
  uint r = (u + 0x7fffu + ((u >> 16) & 1u)) >> 16;
  return (ushort)r;
}
__device__ __forceinline__ float b2f(ushort h) {
  return __uint_as_float(((uint)h) << 16);
}

typedef const __attribute__((address_space(1))) uint* gp1_t;
typedef __attribute__((address_space(3))) uint* lp3_t;
__device__ __forceinline__ void gload16(void* lds, const void* g) {
  __builtin_amdgcn_global_load_lds((gp1_t)g, (lp3_t)lds, 16, 0, 0);
}
// swizzled ds_read: tiles are [row][32 k] bf16, 64B rows, chunk^=(row&3)
__device__ __forceinline__ bf16x8 fragread(const char* lds, int row, int kc) {
  return *(const bf16x8*)(lds + row * 64 + ((kc ^ (row & 3)) << 4));
}

// ---------------- depthwise 3x3 (f32, unchanged) ----------------
__global__ __launch_bounds__(256) void dwconv_k(const float* __restrict__ fmap,
                                                const float* __restrict__ Wdw,
                                                float* __restrict__ dw) {
  __shared__ __align__(16) float sp[4096];
  int c = blockIdx.x, z = blockIdx.y;
  const float* src = fmap + ((size_t)z * Cc + c) * 4096;
  float w[9];
#pragma unroll
  for (int i = 0; i < 9; ++i) w[i] = Wdw[c * 9 + i];
  int t = threadIdx.x;
#pragma unroll
  for (int i = 0; i < 4; ++i)
    *(float4*)&sp[i * 1024 + t * 4] = *(const float4*)&src[i * 1024 + t * 4];
  __syncthreads();
  float* dst = dw + ((size_t)z * Cc + c) * 4096;
  int x = t & 63;
#pragma unroll
  for (int i = 0; i < 16; ++i) {
    int p = i * 256 + t;
    int y = p >> 6;
    float acc = 0.0f;
#pragma unroll
    for (int dy = -1; dy <= 1; ++dy) {
      int yy = y + dy;
      if ((unsigned)yy < 64u) {
#pragma unroll
        for (int dx = -1; dx <= 1; ++dx) {
          int xx = x + dx;
          if ((unsigned)xx < 64u) acc += sp[yy * 64 + xx] * w[(dy + 1) * 3 + (dx + 1)];
        }
      }
    }
    dst[p] = acc;
  }
}

// ---------------- [c][n] f32 -> [n][c] bf16 transpose ----------------
__global__ __launch_bounds__(256) void transp_k(const float* __restrict__ src,
                                                ushort* __restrict__ dst) {
  __shared__ float T[64][65];
  int z = blockIdx.z;
  int c0 = blockIdx.y * 64, n0 = blockIdx.x * 64;
  int t = threadIdx.x;
  const float* s = src + ((size_t)z * Cc + c0) * 4096 + n0;
  int cr = t >> 4, nc = (t & 15) * 4;
#pragma unroll
  for (int it = 0; it < 4; ++it) {
    F4 v; v.v = *(const float4*)&s[(size_t)(cr + it * 16) * 4096 + nc];
#pragma unroll
    for (int j = 0; j < 4; ++j) T[nc + j][cr + it * 16] = v.f[j];
  }
  __syncthreads();
  ushort* d = dst + ((size_t)z * 4096 + n0) * Cc + c0;
  int nr = t >> 2, cc = (t & 3) * 16;
  union { ushort u[16]; uint4 q[2]; } o;
#pragma unroll
  for (int j = 0; j < 16; ++j) o.u[j] = f2bf(T[nr][cc + j]);
  uint4* dp = (uint4*)&d[(size_t)nr * Cc + cc];
  dp[0] = o.q[0]; dp[1] = o.q[1];
}

// ---------------- f32 -> bf16 flat convert (weights) ----------------
__global__ __launch_bounds__(256) void cvtb_k(const float* __restrict__ src,
                                              ushort* __restrict__ dst, int n4) {
  int i = blockIdx.x * 256 + threadIdx.x;
  if (i < n4) {
    F4 v; v.v = *(const float4*)&src[i * 4];
    union { ushort u[4]; uint2 q; } o;
#pragma unroll
    for (int j = 0; j < 4; ++j) o.u[j] = f2bf(v.f[j]);
    *(uint2*)&dst[i * 4] = o.q;
  }
}

// ---------------- NT MFMA GEMM: Y[r][c] = sum_k P[r][k] * Q[c][k] ----------------
// P rows: blockIdx.y*128 .. +128 ; Q rows: blockIdx.x*128 .. +128
template <typename OT, bool BIAS>
__global__ __launch_bounds__(256) void gemm_nt(const ushort* __restrict__ P,
                                               const ushort* __restrict__ Q,
                                               OT* __restrict__ Y,
                                               const float* __restrict__ bias,
                                               int K, long pz, long qz, long yz, int ldy) {
  __shared__ __align__(16) char lds[16384];
  char* LP = lds;
  char* LQ = lds + 8192;
  int t = threadIdx.x, w = t >> 6, l = t & 63;
  int z = blockIdx.z;
  const ushort* Pz = P + (size_t)z * pz + (size_t)(blockIdx.y * 128) * K;
  const ushort* Qz = Q + (size_t)z * qz + (size_t)(blockIdx.x * 128) * K;
  f32x4 acc[4][4];
#pragma unroll
  for (int i = 0; i < 4; ++i)
#pragma unroll
    for (int j = 0; j < 4; ++j) acc[i][j] = (f32x4){0.f, 0.f, 0.f, 0.f};
  int wr = (w >> 1) * 64, wc = (w & 1) * 64;
  int rl = l & 15, kc = l >> 4;
  int srow = (l >> 2) & 15, scol = l & 3;

  for (int k0 = 0; k0 < K; k0 += 32) {
    __syncthreads();
#pragma unroll
    for (int j = 0; j < 2; ++j) {
      int row = (w * 2 + j) * 16 + srow;
      int g = scol ^ (row & 3);
      int off = __builtin_amdgcn_readfirstlane((w * 2 + j) * 1024);
      gload16(LP + off, Pz + (size_t)row * K + k0 + g * 8);
      gload16(LQ + off, Qz + (size_t)row * K + k0 + g * 8);
    }
    asm volatile("s_waitcnt vmcnt(0)" ::: "memory");
    __syncthreads();
    bf16x8 a[4], b[4];
#pragma unroll
    for (int i = 0; i < 4; ++i) a[i] = fragread(LP, wr + i * 16 + rl, kc);
#pragma unroll
    for (int i = 0; i < 4; ++i) b[i] = fragread(LQ, wc + i * 16 + rl, kc);
#pragma unroll
    for (int i = 0; i < 4; ++i)
#pragma unroll
      for (int j = 0; j < 4; ++j)
        acc[i][j] = __builtin_amdgcn_mfma_f32_16x16x32_bf16(a[i], b[j], acc[i][j], 0, 0, 0);
  }
  int r0 = blockIdx.y * 128 + wr, c0 = blockIdx.x * 128 + wc;
  OT* Yz = Y + (size_t)z * yz;
#pragma unroll
  for (int i = 0; i < 4; ++i) {
#pragma unroll
    for (int reg = 0; reg < 4; ++reg) {
      int r = r0 + i * 16 + kc * 4 + reg;
      float bv = BIAS ? bias[r] : 0.f;
#pragma unroll
      for (int j = 0; j < 4; ++j) {
        int c = c0 + j * 16 + rl;
        float v = acc[i][j][reg] + bv;
        if constexpr (sizeof(OT) == 2)
          ((ushort*)Yz)[(size_t)r * ldy + c] = f2bf(v);
        else
          ((float*)Yz)[(size_t)r * ldy + c] = v;
      }
    }
  }
}

// ---------------- q softmax over 64 contiguous features, *0.125 ----------------
__global__ __launch_bounds__(256) void qsm_b(ushort* __restrict__ q) {
  size_t id = (size_t)blockIdx.x * 256 + threadIdx.x;  // (z*4096+n)*8+h
  ushort* p = q + id * 64;
  float f[64];
  float m = -1e30f;
#pragma unroll
  for (int i = 0; i < 8; ++i) {
    bf16x8 v = *(const bf16x8*)&p[i * 8];
#pragma unroll
    for (int j = 0; j < 8; ++j) { f[i * 8 + j] = b2f((ushort)v[j]); m = fmaxf(m, f[i * 8 + j]); }
  }
  float s = 0.f;
#pragma unroll
  for (int i = 0; i < 64; ++i) { f[i] = __expf(f[i] - m); s += f[i]; }
  float inv = 0.125f / s;
#pragma unroll
  for (int i = 0; i < 8; ++i) {
    bf16x8 v;
#pragma unroll
    for (int j = 0; j < 8; ++j) v[j] = (short)f2bf(f[i * 8 + j] * inv);
    *(bf16x8*)&p[i * 8] = v;
  }
}

// ---------------- k softmax over n=4096 (contiguous bf16 row) ----------------
__global__ __launch_bounds__(256) void ksm_b(ushort* __restrict__ kv) {
  int ch = blockIdx.x, z = blockIdx.y;
  ushort* row = kv + ((size_t)z * 2 * TMPc + ch) * 4096;
  int t = threadIdx.x;
  float f[16];
  float m = -1e30f;
#pragma unroll
  for (int p = 0; p < 2; ++p) {
    bf16x8 v = *(const bf16x8*)&row[t * 16 + p * 8];
#pragma unroll
    for (int j = 0; j < 8; ++j) { f[p * 8 + j] = b2f((ushort)v[j]); m = fmaxf(m, f[p * 8 + j]); }
  }
#pragma unroll
  for (int off = 32; off >= 1; off >>= 1) m = fmaxf(m, __shfl_xor(m, off, 64));
  __shared__ float red[8];
  int w = t >> 6;
  if ((t & 63) == 0) red[w] = m;
  __syncthreads();
  m = fmaxf(fmaxf(red[0], red[1]), fmaxf(red[2], red[3]));
  float s = 0.f;
#pragma unroll
  for (int i = 0; i < 16; ++i) { f[i] = __expf(f[i] - m); s += f[i]; }
#pragma unroll
  for (int off = 32; off >= 1; off >>= 1) s += __shfl_xor(s, off, 64);
  if ((t & 63) == 0) red[4 + w] = s;
  __syncthreads();
  float inv = 1.0f / (red[4] + red[5] + red[6] + red[7]);
#pragma unroll
  for (int p = 0; p < 2; ++p) {
    bf16x8 v;
#pragma unroll
    for (int j = 0; j < 8; ++j) v[j] = (short)f2bf(f[p * 8 + j] * inv);
    *(bf16x8*)&row[t * 16 + p * 8] = v;
  }
}

// ---------------- ctxT[e][d] = sum_n v[e][n]*k[d][n] (MFMA, n-split atomics) ----
__global__ __launch_bounds__(256) void ctx_mfma(const ushort* __restrict__ kv,
                                                float* __restrict__ ctxf) {
  __shared__ __align__(16) char lds[8192];  // V tile 4KB | K tile 4KB
  int t = threadIdx.x, w = t >> 6, l = t & 63;
  int s = blockIdx.x;
  int h = blockIdx.y & 7, z = blockIdx.y >> 3;
  const ushort* kb = kv + ((size_t)z * 1024 + h * 64) * 4096;
  const ushort* vb = kv + ((size_t)z * 1024 + 512 + h * 64) * 4096;
  f32x4 acc[2][2];
#pragma unroll
  for (int i = 0; i < 2; ++i)
#pragma unroll
    for (int j = 0; j < 2; ++j) acc[i][j] = (f32x4){0.f, 0.f, 0.f, 0.f};
  int wr = (w >> 1) * 32, wc = (w & 1) * 32;
  int rl = l & 15, kc = l >> 4;
  int srow = (l >> 2) & 15, scol = l & 3;
  for (int it = 0; it < 32; ++it) {
    int k0 = s * 1024 + it * 32;
    __syncthreads();
    {
      int row = w * 16 + srow;
      int g = scol ^ (row & 3);
      int off = __builtin_amdgcn_readfirstlane(w * 1024);
      gload16(lds + off, vb + (size_t)row * 4096 + k0 + g * 8);
      gload16(lds + 4096 + off, kb + (size_t)row * 4096 + k0 + g * 8);
    }
    asm volatile("s_waitcnt vmcnt(0)" ::: "memory");
    __syncthreads();
    bf16x8 a[2], b[2];
#pragma unroll
    for (int i = 0; i < 2; ++i) a[i] = fragread(lds, wr + i * 16 + rl, kc);
#pragma unroll
    for (int i = 0; i < 2; ++i) b[i] = fragread(lds + 4096, wc + i * 16 + rl, kc);
#pragma unroll
    for (int i = 0; i < 2; ++i)
#pragma unroll
      for (int j = 0; j < 2; ++j)
        acc[i][j] = __builtin_amdgcn_mfma_f32_16x16x32_bf16(a[i], b[j], acc[i][j], 0, 0, 0);
  }
  float* cf = ctxf + (size_t)(z * 8 + h) * 4096;
#pragma unroll
  for (int i = 0; i < 2; ++i)
#pragma unroll
    for (int reg = 0; reg < 4; ++reg) {
      int e = wr + i * 16 + kc * 4 + reg;
#pragma unroll
      for (int j = 0; j < 2; ++j) {
        int d = wc + j * 16 + rl;
        atomicAdd(&cf[e * 64 + d], acc[i][j][reg]);
      }
    }
}

// ---------------- ctx f32 -> swizzled bf16 pages ----------------
__global__ __launch_bounds__(256) void ctx_cvt(const float* __restrict__ ctxf,
                                               ushort* __restrict__ cswz) {
  int page = blockIdx.x;
  const float* s = ctxf + (size_t)page * 4096;
  char* d = (char*)(cswz + (size_t)page * 4096);
  int t = threadIdx.x;
  int e = t >> 2, d0 = (t & 3) * 16;
#pragma unroll
  for (int j = 0; j < 16; ++j) {
    int dd = d0 + j;
    int byte = e * 128 + (((dd >> 3) ^ (e & 7)) << 4) + (dd & 7) * 2;
    *(ushort*)(d + byte) = f2bf(s[e * 64 + dd]);
  }
}

// ---------------- attn: goutT[n][h*64+e] = gelu(sum_d q[n][d]*ctxT[e][d]) -------
__global__ __launch_bounds__(256) void attn_mfma(const ushort* __restrict__ qsm,
                                                 const ushort* __restrict__ cswz,
                                                 ushort* __restrict__ goutT) {
  __shared__ __align__(16) char lds[16384 + 8192];
  char* LQt = lds;           // q tile: [128 n][64 d] bf16, 128B rows, 3-bit XOR swizzle
  char* LC = lds + 16384;    // ctx page (already swizzled in global)
  int t = threadIdx.x, w = t >> 6, l = t & 63;
  int h = blockIdx.y & 7, z = blockIdx.y >> 3;
  int n0 = blockIdx.x * 128;
  const float4* cp = (const float4*)(cswz + (size_t)(z * 8 + h) * 4096);
  ((float4*)LC)[t] = cp[t];
  ((float4*)LC)[256 + t] = cp[256 + t];
  const ushort* qz = qsm + (size_t)z * 4096 * 512 + h * 64;
  int srow8 = l >> 3, scol = l & 7;
#pragma unroll
  for (int j = 0; j < 4; ++j) {
    int row = (w * 4 + j) * 8 + srow8;
    int g = scol ^ (row & 7);
    int off = __builtin_amdgcn_readfirstlane((w * 4 + j) * 1024);
    gload16(LQt + off, qz + (size_t)(n0 + row) * 512 + g * 8);
  }
  asm volatile("s_waitcnt vmcnt(0)" ::: "memory");
  __syncthreads();
  int wr = (w >> 1) * 64, wc = (w & 1) * 32;
  int rl = l & 15, kg = l >> 4;
  f32x4 acc[4][2];
#pragma unroll
  for (int i = 0; i < 4; ++i)
#pragma unroll
    for (int j = 0; j < 2; ++j) acc[i][j] = (f32x4){0.f, 0.f, 0.f, 0.f};
#pragma unroll
  for (int ks = 0; ks < 2; ++ks) {
    int chunk = ks * 4 + kg;
    bf16x8 a[4], b[2];
#pragma unroll
    for (int mi = 0; mi < 4; ++mi) {
      int row = wr + mi * 16 + rl;
      a[mi] = *(const bf16x8*)(LQt + row * 128 + ((chunk ^ (row & 7)) << 4));
    }
#pragma unroll
    for (int ci = 0; ci < 2; ++ci) {
      int e = wc + ci * 16 + rl;
      b[ci] = *(const bf16x8*)(LC + e * 128 + ((chunk ^ (e & 7)) << 4));
    }
#pragma unroll
    for (int mi = 0; mi < 4; ++mi)
#pragma unroll
      for (int ci = 0; ci < 2; ++ci)
        acc[mi][ci] = __builtin_amdgcn_mfma_f32_16x16x32_bf16(a[mi], b[ci], acc[mi][ci], 0, 0, 0);
  }
  ushort* gz = goutT + (size_t)z * 4096 * 512 + h * 64;
#pragma unroll
  for (int mi = 0; mi < 4; ++mi)
#pragma unroll
    for (int reg = 0; reg < 4; ++reg) {
      int n = n0 + wr + mi * 16 + kg * 4 + reg;
#pragma unroll
      for (int ci = 0; ci < 2; ++ci) {
        int e = wc + ci * 16 + rl;
        gz[(size_t)n * 512 + e] = f2bf(gelu_exact(acc[mi][ci][reg]));
      }
    }
}

extern "C" void kernel_launch(void* const* d_in, const int* in_sizes, int n_in,
                              void* d_out, int out_size, void* d_ws, size_t ws_size,
                              hipStream_t stream) {
  (void)in_sizes; (void)n_in; (void)out_size;
  const float* fmap = (const float*)d_in[0];
  const float* Wq   = (const float*)d_in[1];
  const float* Wdw  = (const float*)d_in[2];
  const float* Wkv  = (const float*)d_in[3];
  const float* Wout = (const float*)d_in[4];
  const float* bout = (const float*)d_in[5];
  float* out = (float*)d_out;

  // weights (bf16) at start of ws
  ushort* WqB  = (ushort*)d_ws;                 // 512*256
  ushort* WkvB = WqB + 512 * 256;               // 1024*256
  ushort* WoutB = WkvB + 1024 * 256;            // 256*512
  size_t woff = (size_t)(512 * 256 + 1024 * 256 + 256 * 512) * 2;

  // per-batch chunk sizes (bytes)
  auto chunk_bytes = [](int bc) {
    size_t us = (size_t)bc * (4096 * 256 /*fmapT*/ + 4096 * 256 /*dwT*/ +
                              4096 * 512 /*q*/ + 1024 * 4096 /*kv*/ +
                              4096 * 512 /*goutT*/ + 8 * 4096 /*cswz*/) * 2;
    size_t fl = (size_t)bc * (256 * 4096 /*dwf*/ + 8 * 4096 /*ctxf*/) * 4;
    return us + fl;
  };
  int bc = Bx;
  while (bc > 1 && woff + chunk_bytes(bc) > ws_size) bc >>= 1;

  char* base = (char*)d_ws + woff;
  ushort* fmapT = (ushort*)base;
  ushort* dwT   = fmapT + (size_t)bc * 4096 * 256;
  ushort* q     = dwT + (size_t)bc * 4096 * 256;
  ushort* kv    = q + (size_t)bc * 4096 * 512;
  ushort* goutT = kv + (size_t)bc * 1024 * 4096;
  ushort* cswz  = goutT + (size_t)bc * 4096 * 512;
  float*  dwf   = (float*)(cswz + (size_t)bc * 8 * 4096);
  float*  ctxf  = dwf + (size_t)bc * 256 * 4096;

  cvtb_k<<<dim3(512 * 256 / 1024), 256, 0, stream>>>(Wq, WqB, 512 * 256 / 4);
  cvtb_k<<<dim3(1024 * 256 / 1024), 256, 0, stream>>>(Wkv, WkvB, 1024 * 256 / 4);
  cvtb_k<<<dim3(256 * 512 / 1024), 256, 0, stream>>>(Wout, WoutB, 256 * 512 / 4);

  for (int b0 = 0; b0 < Bx; b0 += bc) {
    const float* fchunk = fmap + (size_t)b0 * Cc * Nn;
    transp_k<<<dim3(64, 4, bc), 256, 0, stream>>>(fchunk, fmapT);
    dwconv_k<<<dim3(Cc, bc), 256, 0, stream>>>(fchunk, Wdw, dwf);
    transp_k<<<dim3(64, 4, bc), 256, 0, stream>>>(dwf, dwT);
    // q[n][512] = fmapT[n][k] . WqB[m][k]
    gemm_nt<ushort, false><<<dim3(4, 32, bc), 256, 0, stream>>>(
        fmapT, WqB, q, nullptr, 256, (long)4096 * 256, 0L, (long)4096 * 512, 512);
    // kv[ch][n] = WkvB[ch][k] . dwT[n][k]
    gemm_nt<ushort, false><<<dim3(32, 8, bc), 256, 0, stream>>>(
        WkvB, dwT, kv, nullptr, 256, 0L, (long)4096 * 256, (long)1024 * 4096, 4096);
    qsm_b<<<dim3(bc * 128), 256, 0, stream>>>(q);
    ksm_b<<<dim3(512, bc), 256, 0, stream>>>(kv);
    hipMemsetAsync(ctxf, 0, (size_t)bc * 8 * 4096 * sizeof(float), stream);
    ctx_mfma<<<dim3(4, bc * 8), 256, 0, stream>>>(kv, ctxf);
    ctx_cvt<<<dim3(bc * 8), 256, 0, stream>>>(ctxf, cswz);
    attn_mfma<<<dim3(32, bc * 8), 256, 0, stream>>>(q, cswz, goutT);
    // out[c][n] = WoutB[c][k] . goutT[n][k] + bout
    gemm_nt<float, true><<<dim3(32, 2, bc), 256, 0, stream>>>(
        WoutB, goutT, out + (size_t)b0 * Cc * Nn, bout, 512, 0L, (long)4096 * 512,
        (long)Cc * Nn, 4096);
  }
}

// Round 3
// 152.483 us; speedup vs baseline: 4.1759x; 1.2131x over previous
//
#include <hip/hip_runtime.h>
#include <hip/hip_bf16.h>
#include <math.h>

#define Bx 8
#define Cc 256
#define Nn 4096
#define TMPc 512

typedef unsigned short ushort;
typedef unsigned int uint;
typedef __attribute__((ext_vector_type(8))) short bf16x8;
typedef __attribute__((ext_vector_type(4))) float f32x4;

union F4 { float4 v; float f[4]; };

__device__ __forceinline__ float gelu_exact(float x) {
  return x * 0.5f * (1.0f + erff(x * 0.70710678118654752f));
}
__device__ __forceinline__ ushort f2bf(float x) {
  uint u = __float_as_uint(x);
  uint r = (u + 0x7fffu + ((u >> 16) & 1u)) >> 16;
  return (ushort)r;
}

typedef const __attribute__((address_space(1))) uint* gp1_t;
typedef __attribute__((address_space(3))) uint* lp3_t;
__device__ __forceinline__ void gload16(void* lds, const void* g) {
  __builtin_amdgcn_global_load_lds((gp1_t)g, (lp3_t)lds, 16, 0, 0);
}
// swizzled ds_read: tiles are [row][32 k] bf16, 64B rows, chunk^=(row&3)
__device__ __forceinline__ bf16x8 fragread(const char* lds, int row, int kc) {
  return *(const bf16x8*)(lds + row * 64 + ((kc ^ (row & 3)) << 4));
}

// ---------------- fused: depthwise 3x3 + transpose + bf16 cvt ----------------
// Produces fmapT[n][256] bf16 and dwT[n][256] bf16. Tile: 4 y-rows x 64 x x 32 c.
#define CGRP 32
__global__ __launch_bounds__(256) void convfuse_k(const float* __restrict__ fmap,
                                                  const float* __restrict__ Wdw,
                                                  ushort* __restrict__ fmapT,
                                                  ushort* __restrict__ dwT) {
  __shared__ float sin_[CGRP][6 * 64 + 1];  // c-stride 385 floats (bank-spread)
  __shared__ float wl[CGRP][9];
  int t = threadIdx.x;
  int y0 = blockIdx.x * 4;
  int c0 = blockIdx.y * CGRP;
  int z = blockIdx.z;
  for (int i = t; i < CGRP * 9; i += 256) wl[i / 9][i % 9] = Wdw[c0 * 9 + i];
  const float* src = fmap + ((size_t)z * Cc + c0) * 4096;
#pragma unroll
  for (int it = 0; it < 12; ++it) {
    int idx = it * 256 + t;
    int c = idx / 96, rem = idx % 96, yy = rem >> 4, x4 = rem & 15;
    int gy = y0 - 1 + yy;
    F4 v;
    if ((unsigned)gy < 64u)
      v.v = *(const float4*)&src[(size_t)c * 4096 + gy * 64 + x4 * 4];
    else
      v.f[0] = v.f[1] = v.f[2] = v.f[3] = 0.f;
#pragma unroll
    for (int j = 0; j < 4; ++j) sin_[c][yy * 64 + x4 * 4 + j] = v.f[j];
  }
  __syncthreads();
  int c8 = (t & 3) * 8;
  int nl = t >> 2;  // 0..63
  size_t nbase = (size_t)z * 4096 + (size_t)y0 * 64;
#pragma unroll
  for (int it = 0; it < 4; ++it) {
    int n = it * 64 + nl;
    int y = n >> 6, x = n & 63;
    union { ushort u[8]; uint4 q; } fo, go;
#pragma unroll
    for (int cc = 0; cc < 8; ++cc) {
      int c = c8 + cc;
      fo.u[cc] = f2bf(sin_[c][(y + 1) * 64 + x]);
      float acc = 0.f;
#pragma unroll
      for (int dy = 0; dy < 3; ++dy) {
#pragma unroll
        for (int dx = 0; dx < 3; ++dx) {
          int xx = x + dx - 1;
          float pv = ((unsigned)xx < 64u) ? sin_[c][(y + dy) * 64 + xx] : 0.f;
          acc += pv * wl[c][dy * 3 + dx];
        }
      }
      go.u[cc] = f2bf(acc);
    }
    *(uint4*)&fmapT[(nbase + n) * Cc + c0 + c8] = fo.q;
    *(uint4*)&dwT[(nbase + n) * Cc + c0 + c8] = go.q;
  }
}

// ---------------- f32 -> bf16 flat convert (weights) ----------------
__global__ __launch_bounds__(256) void cvtb_k(const float* __restrict__ src,
                                              ushort* __restrict__ dst, int n4) {
  int i = blockIdx.x * 256 + threadIdx.x;
  if (i < n4) {
    F4 v; v.v = *(const float4*)&src[i * 4];
    union { ushort u[4]; uint2 q; } o;
#pragma unroll
    for (int j = 0; j < 4; ++j) o.u[j] = f2bf(v.f[j]);
    *(uint2*)&dst[i * 4] = o.q;
  }
}

// ---------------- NT MFMA GEMM: Y[r][c] = sum_k P[r][k] * Q[c][k] ----------------
// EPI 0: f32 out + bias. EPI 1: per-row softmax over wave's 64 cols *0.125, bf16.
// EPI 2: exp() for rows < 512, bf16.
template <int EPI>
__global__ __launch_bounds__(256) void gemm_nt(const ushort* __restrict__ P,
                                               const ushort* __restrict__ Q,
                                               void* __restrict__ Yv,
                                               const float* __restrict__ bias,
                                               int K, long pz, long qz, long yz, int ldy) {
  __shared__ __align__(16) char lds[16384];
  char* LP = lds;
  char* LQ = lds + 8192;
  int t = threadIdx.x, w = t >> 6, l = t & 63;
  int z = blockIdx.z;
  const ushort* Pz = P + (size_t)z * pz + (size_t)(blockIdx.y * 128) * K;
  const ushort* Qz = Q + (size_t)z * qz + (size_t)(blockIdx.x * 128) * K;
  f32x4 acc[4][4];
#pragma unroll
  for (int i = 0; i < 4; ++i)
#pragma unroll
    for (int j = 0; j < 4; ++j) acc[i][j] = (f32x4){0.f, 0.f, 0.f, 0.f};
  int wr = (w >> 1) * 64, wc = (w & 1) * 64;
  int rl = l & 15, kc = l >> 4;
  int srow = (l >> 2) & 15, scol = l & 3;

  for (int k0 = 0; k0 < K; k0 += 32) {
    __syncthreads();
#pragma unroll
    for (int j = 0; j < 2; ++j) {
      int row = (w * 2 + j) * 16 + srow;
      int g = scol ^ (row & 3);
      int off = __builtin_amdgcn_readfirstlane((w * 2 + j) * 1024);
      gload16(LP + off, Pz + (size_t)row * K + k0 + g * 8);
      gload16(LQ + off, Qz + (size_t)row * K + k0 + g * 8);
    }
    asm volatile("s_waitcnt vmcnt(0)" ::: "memory");
    __syncthreads();
    bf16x8 a[4], b[4];
#pragma unroll
    for (int i = 0; i < 4; ++i) a[i] = fragread(LP, wr + i * 16 + rl, kc);
#pragma unroll
    for (int i = 0; i < 4; ++i) b[i] = fragread(LQ, wc + i * 16 + rl, kc);
#pragma unroll
    for (int i = 0; i < 4; ++i)
#pragma unroll
      for (int j = 0; j < 4; ++j)
        acc[i][j] = __builtin_amdgcn_mfma_f32_16x16x32_bf16(a[i], b[j], acc[i][j], 0, 0, 0);
  }
  if constexpr (EPI == 1) {
    // per-row softmax over the wave's 64 columns (one head), * 1/sqrt(64)
#pragma unroll
    for (int i = 0; i < 4; ++i) {
#pragma unroll
      for (int reg = 0; reg < 4; ++reg) {
        float m = fmaxf(fmaxf(acc[i][0][reg], acc[i][1][reg]),
                        fmaxf(acc[i][2][reg], acc[i][3][reg]));
#pragma unroll
        for (int off = 1; off < 16; off <<= 1) m = fmaxf(m, __shfl_xor(m, off, 64));
        float e0 = __expf(acc[i][0][reg] - m);
        float e1 = __expf(acc[i][1][reg] - m);
        float e2 = __expf(acc[i][2][reg] - m);
        float e3 = __expf(acc[i][3][reg] - m);
        float s = e0 + e1 + e2 + e3;
#pragma unroll
        for (int off = 1; off < 16; off <<= 1) s += __shfl_xor(s, off, 64);
        float inv = 0.125f / s;
        acc[i][0][reg] = e0 * inv;
        acc[i][1][reg] = e1 * inv;
        acc[i][2][reg] = e2 * inv;
        acc[i][3][reg] = e3 * inv;
      }
    }
  }
  int r0 = blockIdx.y * 128 + wr, c0 = blockIdx.x * 128 + wc;
#pragma unroll
  for (int i = 0; i < 4; ++i) {
#pragma unroll
    for (int reg = 0; reg < 4; ++reg) {
      int r = r0 + i * 16 + kc * 4 + reg;
#pragma unroll
      for (int j = 0; j < 4; ++j) {
        int c = c0 + j * 16 + rl;
        float v = acc[i][j][reg];
        if constexpr (EPI == 0) {
          float* Yz = (float*)Yv + (size_t)z * yz;
          Yz[(size_t)r * ldy + c] = v + bias[r];
        } else if constexpr (EPI == 1) {
          ushort* Yz = (ushort*)Yv + (size_t)z * yz;
          Yz[(size_t)r * ldy + c] = f2bf(v);
        } else {
          ushort* Yz = (ushort*)Yv + (size_t)z * yz;
          Yz[(size_t)r * ldy + c] = f2bf(r < 512 ? __expf(v) : v);
        }
      }
    }
  }
}

// ------- ctxT'[e][d] = sum_n v[e][n]*ek[d][n]; also s[d] = sum_n ek[d][n] -------
__global__ __launch_bounds__(256) void ctx_mfma(const ushort* __restrict__ kv,
                                                float* __restrict__ ctxf,
                                                float* __restrict__ sf) {
  __shared__ __align__(16) char lds[8192];  // V tile 4KB | K tile 4KB
  int t = threadIdx.x, w = t >> 6, l = t & 63;
  int s = blockIdx.x;
  int h = blockIdx.y & 7, z = blockIdx.y >> 3;
  const ushort* kb = kv + ((size_t)z * 1024 + h * 64) * 4096;
  const ushort* vb = kv + ((size_t)z * 1024 + 512 + h * 64) * 4096;
  f32x4 acc[2][2];
  f32x4 accs[2];
#pragma unroll
  for (int i = 0; i < 2; ++i) {
    accs[i] = (f32x4){0.f, 0.f, 0.f, 0.f};
#pragma unroll
    for (int j = 0; j < 2; ++j) acc[i][j] = (f32x4){0.f, 0.f, 0.f, 0.f};
  }
  bf16x8 ones;
#pragma unroll
  for (int i = 0; i < 8; ++i) ones[i] = (short)0x3F80;
  int wr = (w >> 1) * 32, wc = (w & 1) * 32;
  int rl = l & 15, kc = l >> 4;
  int srow = (l >> 2) & 15, scol = l & 3;
  for (int it = 0; it < 32; ++it) {
    int k0 = s * 1024 + it * 32;
    __syncthreads();
    {
      int row = w * 16 + srow;
      int g = scol ^ (row & 3);
      int off = __builtin_amdgcn_readfirstlane(w * 1024);
      gload16(lds + off, vb + (size_t)row * 4096 + k0 + g * 8);
      gload16(lds + 4096 + off, kb + (size_t)row * 4096 + k0 + g * 8);
    }
    asm volatile("s_waitcnt vmcnt(0)" ::: "memory");
    __syncthreads();
    bf16x8 a[2], b[2];
#pragma unroll
    for (int i = 0; i < 2; ++i) a[i] = fragread(lds, wr + i * 16 + rl, kc);
#pragma unroll
    for (int i = 0; i < 2; ++i) b[i] = fragread(lds + 4096, wc + i * 16 + rl, kc);
#pragma unroll
    for (int i = 0; i < 2; ++i)
#pragma unroll
      for (int j = 0; j < 2; ++j)
        acc[i][j] = __builtin_amdgcn_mfma_f32_16x16x32_bf16(a[i], b[j], acc[i][j], 0, 0, 0);
    if (w < 2) {
#pragma unroll
      for (int j = 0; j < 2; ++j)
        accs[j] = __builtin_amdgcn_mfma_f32_16x16x32_bf16(b[j], ones, accs[j], 0, 0, 0);
    }
  }
  float* cf = ctxf + (size_t)(z * 8 + h) * 4096;
#pragma unroll
  for (int i = 0; i < 2; ++i)
#pragma unroll
    for (int reg = 0; reg < 4; ++reg) {
      int e = wr + i * 16 + kc * 4 + reg;
#pragma unroll
      for (int j = 0; j < 2; ++j) {
        int d = wc + j * 16 + rl;
        atomicAdd(&cf[e * 64 + d], acc[i][j][reg]);
      }
    }
  if (w < 2 && rl == 0) {
    float* sp = sf + (size_t)(z * 8 + h) * 64;
#pragma unroll
    for (int j = 0; j < 2; ++j)
#pragma unroll
      for (int reg = 0; reg < 4; ++reg)
        atomicAdd(&sp[wc + j * 16 + kc * 4 + reg], accs[j][reg]);
  }
}

// ---------------- ctx normalize (1/s_d) + f32 -> swizzled bf16 pages ----------------
__global__ __launch_bounds__(256) void ctx_cvt(const float* __restrict__ ctxf,
                                               const float* __restrict__ sf,
                                               ushort* __restrict__ cswz) {
  int page = blockIdx.x;
  const float* s = ctxf + (size_t)page * 4096;
  const float* sp = sf + (size_t)page * 64;
  char* d = (char*)(cswz + (size_t)page * 4096);
  int t = threadIdx.x;
  int e = t >> 2, d0 = (t & 3) * 16;
#pragma unroll
  for (int j = 0; j < 16; ++j) {
    int dd = d0 + j;
    int byte = e * 128 + (((dd >> 3) ^ (e & 7)) << 4) + (dd & 7) * 2;
    *(ushort*)(d + byte) = f2bf(s[e * 64 + dd] / sp[dd]);
  }
}

// ---------------- attn: goutT[n][h*64+e] = gelu(sum_d q[n][d]*ctxT[e][d]) -------
__global__ __launch_bounds__(256) void attn_mfma(const ushort* __restrict__ qsm,
                                                 const ushort* __restrict__ cswz,
                                                 ushort* __restrict__ goutT) {
  __shared__ __align__(16) char lds[16384 + 8192];
  char* LQt = lds;
  char* LC = lds + 16384;
  int t = threadIdx.x, w = t >> 6, l = t & 63;
  int h = blockIdx.y & 7, z = blockIdx.y >> 3;
  int n0 = blockIdx.x * 128;
  const float4* cp = (const float4*)(cswz + (size_t)(z * 8 + h) * 4096);
  ((float4*)LC)[t] = cp[t];
  ((float4*)LC)[256 + t] = cp[256 + t];
  const ushort* qz = qsm + (size_t)z * 4096 * 512 + h * 64;
  int srow8 = l >> 3, scol = l & 7;
#pragma unroll
  for (int j = 0; j < 4; ++j) {
    int row = (w * 4 + j) * 8 + srow8;
    int g = scol ^ (row & 7);
    int off = __builtin_amdgcn_readfirstlane((w * 4 + j) * 1024);
    gload16(LQt + off, qz + (size_t)(n0 + row) * 512 + g * 8);
  }
  asm volatile("s_waitcnt vmcnt(0)" ::: "memory");
  __syncthreads();
  int wr = (w >> 1) * 64, wc = (w & 1) * 32;
  int rl = l & 15, kg = l >> 4;
  f32x4 acc[4][2];
#pragma unroll
  for (int i = 0; i < 4; ++i)
#pragma unroll
    for (int j = 0; j < 2; ++j) acc[i][j] = (f32x4){0.f, 0.f, 0.f, 0.f};
#pragma unroll
  for (int ks = 0; ks < 2; ++ks) {
    int chunk = ks * 4 + kg;
    bf16x8 a[4], b[2];
#pragma unroll
    for (int mi = 0; mi < 4; ++mi) {
      int row = wr + mi * 16 + rl;
      a[mi] = *(const bf16x8*)(LQt + row * 128 + ((chunk ^ (row & 7)) << 4));
    }
#pragma unroll
    for (int ci = 0; ci < 2; ++ci) {
      int e = wc + ci * 16 + rl;
      b[ci] = *(const bf16x8*)(LC + e * 128 + ((chunk ^ (e & 7)) << 4));
    }
#pragma unroll
    for (int mi = 0; mi < 4; ++mi)
#pragma unroll
      for (int ci = 0; ci < 2; ++ci)
        acc[mi][ci] = __builtin_amdgcn_mfma_f32_16x16x32_bf16(a[mi], b[ci], acc[mi][ci], 0, 0, 0);
  }
  ushort* gz = goutT + (size_t)z * 4096 * 512 + h * 64;
#pragma unroll
  for (int mi = 0; mi < 4; ++mi)
#pragma unroll
    for (int reg = 0; reg < 4; ++reg) {
      int n = n0 + wr + mi * 16 + kg * 4 + reg;
#pragma unroll
      for (int ci = 0; ci < 2; ++ci) {
        int e = wc + ci * 16 + rl;
        gz[(size_t)n * 512 + e] = f2bf(gelu_exact(acc[mi][ci][reg]));
      }
    }
}

extern "C" void kernel_launch(void* const* d_in, const int* in_sizes, int n_in,
                              void* d_out, int out_size, void* d_ws, size_t ws_size,
                              hipStream_t stream) {
  (void)in_sizes; (void)n_in; (void)out_size; (void)ws_size;
  const float* fmap = (const float*)d_in[0];
  const float* Wq   = (const float*)d_in[1];
  const float* Wdw  = (const float*)d_in[2];
  const float* Wkv  = (const float*)d_in[3];
  const float* Wout = (const float*)d_in[4];
  const float* bout = (const float*)d_in[5];
  float* out = (float*)d_out;

  ushort* WqB   = (ushort*)d_ws;
  ushort* WkvB  = WqB + 512 * 256;
  ushort* WoutB = WkvB + 1024 * 256;
  ushort* fmapT = WoutB + 256 * 512;
  ushort* dwT   = fmapT + (size_t)Bx * 4096 * 256;
  ushort* q     = dwT + (size_t)Bx * 4096 * 256;
  ushort* kv    = q + (size_t)Bx * 4096 * 512;
  ushort* goutT = kv + (size_t)Bx * 1024 * 4096;
  ushort* cswz  = goutT + (size_t)Bx * 4096 * 512;
  float*  ctxf  = (float*)(cswz + (size_t)Bx * 8 * 4096);
  float*  sf    = ctxf + (size_t)Bx * 8 * 64 * 64;

  cvtb_k<<<dim3(512 * 256 / 1024), 256, 0, stream>>>(Wq, WqB, 512 * 256 / 4);
  cvtb_k<<<dim3(1024 * 256 / 1024), 256, 0, stream>>>(Wkv, WkvB, 1024 * 256 / 4);
  cvtb_k<<<dim3(256 * 512 / 1024), 256, 0, stream>>>(Wout, WoutB, 256 * 512 / 4);

  convfuse_k<<<dim3(16, Cc / CGRP, Bx), 256, 0, stream>>>(fmap, Wdw, fmapT, dwT);
  // q[n][512] = fmapT[n][k] . WqB[m][k], fused q-softmax
  gemm_nt<1><<<dim3(4, 32, Bx), 256, 0, stream>>>(
      fmapT, WqB, q, nullptr, 256, (long)4096 * 256, 0L, (long)4096 * 512, 512);
  // kv[ch][n] = WkvB[ch][k] . dwT[n][k], exp() on k-half
  gemm_nt<2><<<dim3(32, 8, Bx), 256, 0, stream>>>(
      WkvB, dwT, kv, nullptr, 256, 0L, (long)4096 * 256, (long)1024 * 4096, 4096);
  hipMemsetAsync(ctxf, 0, (size_t)Bx * 8 * (4096 + 64) * sizeof(float), stream);
  ctx_mfma<<<dim3(4, Bx * 8), 256, 0, stream>>>(kv, ctxf, sf);
  ctx_cvt<<<dim3(Bx * 8), 256, 0, stream>>>(ctxf, sf, cswz);
  attn_mfma<<<dim3(32, Bx * 8), 256, 0, stream>>>(q, cswz, goutT);
  // out[c][n] = WoutB[c][k] . goutT[n][k] + bout
  gemm_nt<0><<<dim3(32, 2, Bx), 256, 0, stream>>>(
      WoutB, goutT, out, bout, 512, 0L, (long)4096 * 512, (long)Cc * Nn, 4096);
}

// Round 4
// 146.516 us; speedup vs baseline: 4.3459x; 1.0407x over previous
//
#include <hip/hip_runtime.h>
#include <hip/hip_bf16.h>
#include <math.h>

#define Bx 8
#define Cc 256
#define Nn 4096
#define TMPc 512

typedef unsigned short ushort;
typedef unsigned int uint;
typedef __attribute__((ext_vector_type(8))) short bf16x8;
typedef __attribute__((ext_vector_type(4))) float f32x4;

union F4 { float4 v; float f[4]; };

__device__ __forceinline__ float gelu_exact(float x) {
  return x * 0.5f * (1.0f + erff(x * 0.70710678118654752f));
}
__device__ __forceinline__ ushort f2bf(float x) {
  uint u = __float_as_uint(x);
  uint r = (u + 0x7fffu + ((u >> 16) & 1u)) >> 16;
  return (ushort)r;
}

typedef const __attribute__((address_space(1))) uint* gp1_t;
typedef __attribute__((address_space(3))) uint* lp3_t;
__device__ __forceinline__ void gload16(void* lds, const void* g) {
  __builtin_amdgcn_global_load_lds((gp1_t)g, (lp3_t)lds, 16, 0, 0);
}
// swizzled ds_read: tiles are [row][32 k] bf16, 64B rows, chunk^=(row&3)
__device__ __forceinline__ bf16x8 fragread(const char* lds, int row, int kc) {
  return *(const bf16x8*)(lds + row * 64 + ((kc ^ (row & 3)) << 4));
}

// ---------------- fused: depthwise 3x3 + transpose + bf16 cvt ----------------
#define CGRP 32
__global__ __launch_bounds__(256) void convfuse_k(const float* __restrict__ fmap,
                                                  const float* __restrict__ Wdw,
                                                  ushort* __restrict__ fmapT,
                                                  ushort* __restrict__ dwT) {
  __shared__ float sin_[CGRP][6 * 64 + 1];
  __shared__ float wl[CGRP][9];
  int t = threadIdx.x;
  int y0 = blockIdx.x * 4;
  int c0 = blockIdx.y * CGRP;
  int z = blockIdx.z;
  for (int i = t; i < CGRP * 9; i += 256) wl[i / 9][i % 9] = Wdw[c0 * 9 + i];
  const float* src = fmap + ((size_t)z * Cc + c0) * 4096;
#pragma unroll
  for (int it = 0; it < 12; ++it) {
    int idx = it * 256 + t;
    int c = idx / 96, rem = idx % 96, yy = rem >> 4, x4 = rem & 15;
    int gy = y0 - 1 + yy;
    F4 v;
    if ((unsigned)gy < 64u)
      v.v = *(const float4*)&src[(size_t)c * 4096 + gy * 64 + x4 * 4];
    else
      v.f[0] = v.f[1] = v.f[2] = v.f[3] = 0.f;
#pragma unroll
    for (int j = 0; j < 4; ++j) sin_[c][yy * 64 + x4 * 4 + j] = v.f[j];
  }
  __syncthreads();
  int c8 = (t & 3) * 8;
  int nl = t >> 2;
  size_t nbase = (size_t)z * 4096 + (size_t)y0 * 64;
#pragma unroll
  for (int it = 0; it < 4; ++it) {
    int n = it * 64 + nl;
    int y = n >> 6, x = n & 63;
    union { ushort u[8]; uint4 q; } fo, go;
#pragma unroll
    for (int cc = 0; cc < 8; ++cc) {
      int c = c8 + cc;
      fo.u[cc] = f2bf(sin_[c][(y + 1) * 64 + x]);
      float acc = 0.f;
#pragma unroll
      for (int dy = 0; dy < 3; ++dy) {
#pragma unroll
        for (int dx = 0; dx < 3; ++dx) {
          int xx = x + dx - 1;
          float pv = ((unsigned)xx < 64u) ? sin_[c][(y + dy) * 64 + xx] : 0.f;
          acc += pv * wl[c][dy * 3 + dx];
        }
      }
      go.u[cc] = f2bf(acc);
    }
    *(uint4*)&fmapT[(nbase + n) * Cc + c0 + c8] = fo.q;
    *(uint4*)&dwT[(nbase + n) * Cc + c0 + c8] = go.q;
  }
}

// ---------------- all three weights f32 -> bf16 in one launch ----------------
__global__ __launch_bounds__(256) void cvtb3_k(const float* __restrict__ Wq,
                                               const float* __restrict__ Wkv,
                                               const float* __restrict__ Wout,
                                               ushort* __restrict__ WqB,
                                               ushort* __restrict__ WkvB,
                                               ushort* __restrict__ WoutB) {
  int i = blockIdx.x * 256 + threadIdx.x;  // 4 floats each; total 131072 groups
  const float* s;
  ushort* d;
  int idx;
  if (i < 32768) { s = Wq; d = WqB; idx = i; }
  else if (i < 98304) { s = Wkv; d = WkvB; idx = i - 32768; }
  else { s = Wout; d = WoutB; idx = i - 98304; }
  F4 v; v.v = *(const float4*)&s[(size_t)idx * 4];
  union { ushort u[4]; uint2 q; } o;
#pragma unroll
  for (int j = 0; j < 4; ++j) o.u[j] = f2bf(v.f[j]);
  *(uint2*)&d[(size_t)idx * 4] = o.q;
}

// ------- kv GEMM: kv[ch][n] = Wkv[ch][k] . dwT[n][k]; exp() on k-half --------
__global__ __launch_bounds__(256) void kvgemm_k(const ushort* __restrict__ P,
                                                const ushort* __restrict__ Q,
                                                ushort* __restrict__ Y,
                                                long qz, long yz) {
  __shared__ __align__(16) char lds[16384];
  char* LP = lds;
  char* LQ = lds + 8192;
  int t = threadIdx.x, w = t >> 6, l = t & 63;
  int z = blockIdx.z;
  const ushort* Pz = P + (size_t)(blockIdx.y * 128) * 256;
  const ushort* Qz = Q + (size_t)z * qz + (size_t)(blockIdx.x * 128) * 256;
  f32x4 acc[4][4];
#pragma unroll
  for (int i = 0; i < 4; ++i)
#pragma unroll
    for (int j = 0; j < 4; ++j) acc[i][j] = (f32x4){0.f, 0.f, 0.f, 0.f};
  int wr = (w >> 1) * 64, wc = (w & 1) * 64;
  int rl = l & 15, kc = l >> 4;
  int srow = (l >> 2) & 15, scol = l & 3;

  for (int k0 = 0; k0 < 256; k0 += 32) {
    __syncthreads();
#pragma unroll
    for (int j = 0; j < 2; ++j) {
      int row = (w * 2 + j) * 16 + srow;
      int g = scol ^ (row & 3);
      int off = __builtin_amdgcn_readfirstlane((w * 2 + j) * 1024);
      gload16(LP + off, Pz + (size_t)row * 256 + k0 + g * 8);
      gload16(LQ + off, Qz + (size_t)row * 256 + k0 + g * 8);
    }
    asm volatile("s_waitcnt vmcnt(0)" ::: "memory");
    __syncthreads();
    bf16x8 a[4], b[4];
#pragma unroll
    for (int i = 0; i < 4; ++i) a[i] = fragread(LP, wr + i * 16 + rl, kc);
#pragma unroll
    for (int i = 0; i < 4; ++i) b[i] = fragread(LQ, wc + i * 16 + rl, kc);
#pragma unroll
    for (int i = 0; i < 4; ++i)
#pragma unroll
      for (int j = 0; j < 4; ++j)
        acc[i][j] = __builtin_amdgcn_mfma_f32_16x16x32_bf16(a[i], b[j], acc[i][j], 0, 0, 0);
  }
  int r0 = blockIdx.y * 128 + wr, c0 = blockIdx.x * 128 + wc;
  ushort* Yz = Y + (size_t)z * yz;
#pragma unroll
  for (int i = 0; i < 4; ++i) {
#pragma unroll
    for (int reg = 0; reg < 4; ++reg) {
      int r = r0 + i * 16 + kc * 4 + reg;
#pragma unroll
      for (int j = 0; j < 4; ++j) {
        int c = c0 + j * 16 + rl;
        float v = acc[i][j][reg];
        Yz[(size_t)r * 4096 + c] = f2bf(r < 512 ? __expf(v) : v);
      }
    }
  }
}

// ------- ctxT'[e][d] = sum_n v[e][n]*ek[d][n]; also s[d] = sum_n ek[d][n] -------
__global__ __launch_bounds__(256) void ctx_mfma(const ushort* __restrict__ kv,
                                                float* __restrict__ ctxf,
                                                float* __restrict__ sf) {
  __shared__ __align__(16) char lds[8192];
  int t = threadIdx.x, w = t >> 6, l = t & 63;
  int s = blockIdx.x;
  int h = blockIdx.y & 7, z = blockIdx.y >> 3;
  const ushort* kb = kv + ((size_t)z * 1024 + h * 64) * 4096;
  const ushort* vb = kv + ((size_t)z * 1024 + 512 + h * 64) * 4096;
  f32x4 acc[2][2];
  f32x4 accs[2];
#pragma unroll
  for (int i = 0; i < 2; ++i) {
    accs[i] = (f32x4){0.f, 0.f, 0.f, 0.f};
#pragma unroll
    for (int j = 0; j < 2; ++j) acc[i][j] = (f32x4){0.f, 0.f, 0.f, 0.f};
  }
  bf16x8 ones;
#pragma unroll
  for (int i = 0; i < 8; ++i) ones[i] = (short)0x3F80;
  int wr = (w >> 1) * 32, wc = (w & 1) * 32;
  int rl = l & 15, kc = l >> 4;
  int srow = (l >> 2) & 15, scol = l & 3;
  for (int it = 0; it < 32; ++it) {
    int k0 = s * 1024 + it * 32;
    __syncthreads();
    {
      int row = w * 16 + srow;
      int g = scol ^ (row & 3);
      int off = __builtin_amdgcn_readfirstlane(w * 1024);
      gload16(lds + off, vb + (size_t)row * 4096 + k0 + g * 8);
      gload16(lds + 4096 + off, kb + (size_t)row * 4096 + k0 + g * 8);
    }
    asm volatile("s_waitcnt vmcnt(0)" ::: "memory");
    __syncthreads();
    bf16x8 a[2], b[2];
#pragma unroll
    for (int i = 0; i < 2; ++i) a[i] = fragread(lds, wr + i * 16 + rl, kc);
#pragma unroll
    for (int i = 0; i < 2; ++i) b[i] = fragread(lds + 4096, wc + i * 16 + rl, kc);
#pragma unroll
    for (int i = 0; i < 2; ++i)
#pragma unroll
      for (int j = 0; j < 2; ++j)
        acc[i][j] = __builtin_amdgcn_mfma_f32_16x16x32_bf16(a[i], b[j], acc[i][j], 0, 0, 0);
    if (w < 2) {
#pragma unroll
      for (int j = 0; j < 2; ++j)
        accs[j] = __builtin_amdgcn_mfma_f32_16x16x32_bf16(b[j], ones, accs[j], 0, 0, 0);
    }
  }
  float* cf = ctxf + (size_t)(z * 8 + h) * 4096;
#pragma unroll
  for (int i = 0; i < 2; ++i)
#pragma unroll
    for (int reg = 0; reg < 4; ++reg) {
      int e = wr + i * 16 + kc * 4 + reg;
#pragma unroll
      for (int j = 0; j < 2; ++j) {
        int d = wc + j * 16 + rl;
        atomicAdd(&cf[e * 64 + d], acc[i][j][reg]);
      }
    }
  if (w < 2 && rl == 0) {
    float* sp = sf + (size_t)(z * 8 + h) * 64;
#pragma unroll
    for (int j = 0; j < 2; ++j)
#pragma unroll
      for (int reg = 0; reg < 4; ++reg)
        atomicAdd(&sp[wc + j * 16 + kc * 4 + reg], accs[j][reg]);
  }
}

// ------------- ctx normalize (1/s_d) + f32 -> swizzled bf16 pages -------------
__global__ __launch_bounds__(256) void ctx_cvt(const float* __restrict__ ctxf,
                                               const float* __restrict__ sf,
                                               ushort* __restrict__ cswz) {
  int page = blockIdx.x;
  const float* s = ctxf + (size_t)page * 4096;
  const float* sp = sf + (size_t)page * 64;
  char* d = (char*)(cswz + (size_t)page * 4096);
  int t = threadIdx.x;
  int e = t >> 2, d0 = (t & 3) * 16;
#pragma unroll
  for (int j = 0; j < 16; ++j) {
    int dd = d0 + j;
    int byte = e * 128 + (((dd >> 3) ^ (e & 7)) << 4) + (dd & 7) * 2;
    *(ushort*)(d + byte) = f2bf(s[e * 64 + dd] / sp[dd]);
  }
}

// ======== MEGA: q-GEMM -> q-softmax -> PV(ctx) -> GELU -> out-GEMM ========
// block: 128 n-rows x z. LDS: qbuf 32KB | Asg 16KB | Bsg 8KB.
__global__ __launch_bounds__(256) void qao_k(const ushort* __restrict__ fmapT,
                                             const ushort* __restrict__ WqB,
                                             const ushort* __restrict__ cswz,
                                             const ushort* __restrict__ WoutB,
                                             const float* __restrict__ bout,
                                             float* __restrict__ out) {
  __shared__ __align__(16) char lds[57344];
  char* qbuf = lds;          // [128 n][128 d] bf16, 256B rows, XOR (n&7)<<4
  char* Asg = lds + 32768;   // 16KB staging (Wq tile / ctx pages / Wout tile)
  char* Bsg = lds + 49152;   // 8KB staging (fmapT tile)
  int t = threadIdx.x, w = t >> 6, l = t & 63;
  int z = blockIdx.y, n0 = blockIdx.x * 128;
  int rl = l & 15, kc = l >> 4;
  int srow = (l >> 2) & 15, scol = l & 3;
  int wr = (w >> 1) * 64, wc = (w & 1) * 64;

  f32x4 oacc[4][8];  // rows c = w*64+16i+4kc+reg, cols n = 16j+rl
#pragma unroll
  for (int i = 0; i < 4; ++i)
#pragma unroll
    for (int j = 0; j < 8; ++j) oacc[i][j] = (f32x4){0.f, 0.f, 0.f, 0.f};

  const ushort* fT = fmapT + ((size_t)z * 4096 + n0) * 256;

  for (int c = 0; c < 4; ++c) {
    // ---- q-GEMM chunk: Y[128 d][128 n], K=256
    f32x4 qa[4][4];
#pragma unroll
    for (int i = 0; i < 4; ++i)
#pragma unroll
      for (int j = 0; j < 4; ++j) qa[i][j] = (f32x4){0.f, 0.f, 0.f, 0.f};
    const ushort* Wqc = WqB + (size_t)(c * 128) * 256;
    for (int k0 = 0; k0 < 256; k0 += 32) {
      __syncthreads();
#pragma unroll
      for (int j = 0; j < 2; ++j) {
        int row = (w * 2 + j) * 16 + srow;
        int g = scol ^ (row & 3);
        int off = __builtin_amdgcn_readfirstlane((w * 2 + j) * 1024);
        gload16(Asg + off, Wqc + (size_t)row * 256 + k0 + g * 8);
        gload16(Bsg + off, fT + (size_t)row * 256 + k0 + g * 8);
      }
      asm volatile("s_waitcnt vmcnt(0)" ::: "memory");
      __syncthreads();
      bf16x8 a[4], b[4];
#pragma unroll
      for (int i = 0; i < 4; ++i) a[i] = fragread(Asg, wr + i * 16 + rl, kc);
#pragma unroll
      for (int i = 0; i < 4; ++i) b[i] = fragread(Bsg, wc + i * 16 + rl, kc);
#pragma unroll
      for (int i = 0; i < 4; ++i)
#pragma unroll
        for (int j = 0; j < 4; ++j)
          qa[i][j] = __builtin_amdgcn_mfma_f32_16x16x32_bf16(a[i], b[j], qa[i][j], 0, 0, 0);
    }
    __syncthreads();  // all frag reads done; Asg free for ctx
    // ---- issue ctx page loads (2 heads, 16KB linear) to overlap softmax
    {
      const char* cp = (const char*)cswz + ((size_t)(z * 8 + c * 2)) * 8192;
#pragma unroll
      for (int r = 0; r < 4; ++r) {
        int off = __builtin_amdgcn_readfirstlane(w * 4096 + r * 1024);
        gload16(Asg + off, cp + off + l * 16);
      }
    }
    // ---- softmax over d (64 rows of this wave's head) per column
#pragma unroll
    for (int j = 0; j < 4; ++j) {
      float m = -1e30f;
#pragma unroll
      for (int i = 0; i < 4; ++i)
#pragma unroll
        for (int r = 0; r < 4; ++r) m = fmaxf(m, qa[i][j][r]);
      m = fmaxf(m, __shfl_xor(m, 16, 64));
      m = fmaxf(m, __shfl_xor(m, 32, 64));
      float s = 0.f;
#pragma unroll
      for (int i = 0; i < 4; ++i)
#pragma unroll
        for (int r = 0; r < 4; ++r) {
          float e = __expf(qa[i][j][r] - m);
          qa[i][j][r] = e;
          s += e;
        }
      s += __shfl_xor(s, 16, 64);
      s += __shfl_xor(s, 32, 64);
      float inv = 0.125f / s;
#pragma unroll
      for (int i = 0; i < 4; ++i)
#pragma unroll
        for (int r = 0; r < 4; ++r) qa[i][j][r] *= inv;
    }
    // ---- write q to qbuf [n][d] (b64 packed, swizzled)
#pragma unroll
    for (int i = 0; i < 4; ++i)
#pragma unroll
      for (int j = 0; j < 4; ++j) {
        int n = wc + 16 * j + rl;
        int dby = (wr + 16 * i + 4 * kc) * 2;
        union { ushort u[4]; unsigned long long q; } pk;
#pragma unroll
        for (int r = 0; r < 4; ++r) pk.u[r] = f2bf(qa[i][j][r]);
        *(unsigned long long*)(qbuf + n * 256 + (dby ^ ((n & 7) << 4))) = pk.q;
      }
    asm volatile("s_waitcnt vmcnt(0)" ::: "memory");
    __syncthreads();
    // ---- PV: Y[e 128][n 128] per head (block-diagonal K=64)
    f32x4 pacc[4][4];
#pragma unroll
    for (int i = 0; i < 4; ++i)
#pragma unroll
      for (int j = 0; j < 4; ++j) pacc[i][j] = (f32x4){0.f, 0.f, 0.f, 0.f};
    const char* ctxpg = Asg + (w >> 1) * 8192;
#pragma unroll
    for (int s = 0; s < 2; ++s) {
      bf16x8 a[4], b[4];
#pragma unroll
      for (int i = 0; i < 4; ++i) {
        int e = 16 * i + rl;
        a[i] = *(const bf16x8*)(ctxpg + e * 128 + ((((s * 4 + kc) << 4)) ^ ((e & 7) << 4)));
      }
#pragma unroll
      for (int j = 0; j < 4; ++j) {
        int n = wc + 16 * j + rl;
        int kb = (w >> 1) * 128 + s * 64 + kc * 16;
        b[j] = *(const bf16x8*)(qbuf + n * 256 + (kb ^ ((n & 7) << 4)));
      }
#pragma unroll
      for (int i = 0; i < 4; ++i)
#pragma unroll
        for (int j = 0; j < 4; ++j)
          pacc[i][j] = __builtin_amdgcn_mfma_f32_16x16x32_bf16(a[i], b[j], pacc[i][j], 0, 0, 0);
    }
    __syncthreads();  // qbuf reads done before overwrite
    // ---- GELU -> gout into qbuf [n][m-local]
#pragma unroll
    for (int i = 0; i < 4; ++i)
#pragma unroll
      for (int j = 0; j < 4; ++j) {
        int n = wc + 16 * j + rl;
        int mby = (wr + 16 * i + 4 * kc) * 2;
        union { ushort u[4]; unsigned long long q; } pk;
#pragma unroll
        for (int r = 0; r < 4; ++r) pk.u[r] = f2bf(gelu_exact(pacc[i][j][r]));
        *(unsigned long long*)(qbuf + n * 256 + (mby ^ ((n & 7) << 4))) = pk.q;
      }
    __syncthreads();
    // ---- out-GEMM partial: oacc[256 c][128 n] += Wout[:, c*128..] . gout^T
    for (int ks = 0; ks < 4; ++ks) {
      if (ks) __syncthreads();
#pragma unroll
      for (int jj = 0; jj < 4; ++jj) {
        int row = (w * 4 + jj) * 16 + srow;
        int g = scol ^ (row & 3);
        int off = __builtin_amdgcn_readfirstlane((w * 4 + jj) * 1024);
        gload16(Asg + off, WoutB + (size_t)row * 512 + c * 128 + ks * 32 + g * 8);
      }
      asm volatile("s_waitcnt vmcnt(0)" ::: "memory");
      __syncthreads();
      bf16x8 a[4], b[8];
#pragma unroll
      for (int i = 0; i < 4; ++i) a[i] = fragread(Asg, w * 64 + 16 * i + rl, kc);
#pragma unroll
      for (int j = 0; j < 8; ++j) {
        int n = 16 * j + rl;
        b[j] = *(const bf16x8*)(qbuf + n * 256 + ((ks * 64 + kc * 16) ^ ((n & 7) << 4)));
      }
#pragma unroll
      for (int i = 0; i < 4; ++i)
#pragma unroll
        for (int j = 0; j < 8; ++j)
          oacc[i][j] = __builtin_amdgcn_mfma_f32_16x16x32_bf16(a[i], b[j], oacc[i][j], 0, 0, 0);
    }
    __syncthreads();  // qbuf/Asg reads done before next chunk
  }
  // ---- epilogue: bias + f32 store
  float* oz = out + (size_t)z * Cc * Nn + n0;
#pragma unroll
  for (int i = 0; i < 4; ++i) {
#pragma unroll
    for (int r = 0; r < 4; ++r) {
      int crow = w * 64 + 16 * i + 4 * kc + r;
      float bv = bout[crow];
      float* rowp = oz + (size_t)crow * 4096;
#pragma unroll
      for (int j = 0; j < 8; ++j) rowp[16 * j + rl] = oacc[i][j][r] + bv;
    }
  }
}

extern "C" void kernel_launch(void* const* d_in, const int* in_sizes, int n_in,
                              void* d_out, int out_size, void* d_ws, size_t ws_size,
                              hipStream_t stream) {
  (void)in_sizes; (void)n_in; (void)out_size; (void)ws_size;
  const float* fmap = (const float*)d_in[0];
  const float* Wq   = (const float*)d_in[1];
  const float* Wdw  = (const float*)d_in[2];
  const float* Wkv  = (const float*)d_in[3];
  const float* Wout = (const float*)d_in[4];
  const float* bout = (const float*)d_in[5];
  float* out = (float*)d_out;

  ushort* WqB   = (ushort*)d_ws;
  ushort* WkvB  = WqB + 512 * 256;
  ushort* WoutB = WkvB + 1024 * 256;
  ushort* fmapT = WoutB + 256 * 512;
  ushort* dwT   = fmapT + (size_t)Bx * 4096 * 256;
  ushort* kv    = dwT + (size_t)Bx * 4096 * 256;
  ushort* cswz  = kv + (size_t)Bx * 1024 * 4096;
  float*  ctxf  = (float*)(cswz + (size_t)Bx * 8 * 4096);
  float*  sf    = ctxf + (size_t)Bx * 8 * 64 * 64;

  cvtb3_k<<<dim3(512), 256, 0, stream>>>(Wq, Wkv, Wout, WqB, WkvB, WoutB);
  convfuse_k<<<dim3(16, Cc / CGRP, Bx), 256, 0, stream>>>(fmap, Wdw, fmapT, dwT);
  kvgemm_k<<<dim3(32, 8, Bx), 256, 0, stream>>>(
      WkvB, dwT, kv, (long)4096 * 256, (long)1024 * 4096);
  hipMemsetAsync(ctxf, 0, (size_t)Bx * 8 * (4096 + 64) * sizeof(float), stream);
  ctx_mfma<<<dim3(4, Bx * 8), 256, 0, stream>>>(kv, ctxf, sf);
  ctx_cvt<<<dim3(Bx * 8), 256, 0, stream>>>(ctxf, sf, cswz);
  qao_k<<<dim3(32, Bx), 256, 0, stream>>>(fmapT, WqB, cswz, WoutB, bout, out);
}

// Round 5
// 127.277 us; speedup vs baseline: 5.0029x; 1.1512x over previous
//
#include <hip/hip_runtime.h>
#include <hip/hip_bf16.h>
#include <math.h>

#define Bx 8
#define Cc 256
#define Nn 4096
#define TMPc 512

typedef unsigned short ushort;
typedef unsigned int uint;
typedef __attribute__((ext_vector_type(8))) short bf16x8;
typedef __attribute__((ext_vector_type(4))) float f32x4;

union F4 { float4 v; float f[4]; };

__device__ __forceinline__ float gelu_exact(float x) {
  return x * 0.5f * (1.0f + erff(x * 0.70710678118654752f));
}
__device__ __forceinline__ ushort f2bf(float x) {
  uint u = __float_as_uint(x);
  uint r = (u + 0x7fffu + ((u >> 16) & 1u)) >> 16;
  return (ushort)r;
}

typedef const __attribute__((address_space(1))) uint* gp1_t;
typedef __attribute__((address_space(3))) uint* lp3_t;
__device__ __forceinline__ void gload16(void* lds, const void* g) {
  __builtin_amdgcn_global_load_lds((gp1_t)g, (lp3_t)lds, 16, 0, 0);
}
// swizzled ds_read: tiles are [row][32 k] bf16, 64B rows, chunk^=(row&3)
__device__ __forceinline__ bf16x8 fragread(const char* lds, int row, int kc) {
  return *(const bf16x8*)(lds + row * 64 + ((kc ^ (row & 3)) << 4));
}

// ---------------- fused: depthwise 3x3 + transpose + bf16 cvt ----------------
#define CGRP 32
__global__ __launch_bounds__(256) void convfuse_k(const float* __restrict__ fmap,
                                                  const float* __restrict__ Wdw,
                                                  ushort* __restrict__ fmapT,
                                                  ushort* __restrict__ dwT) {
  __shared__ float sin_[CGRP][6 * 64 + 1];
  __shared__ float wl[CGRP][9];
  int t = threadIdx.x;
  int y0 = blockIdx.x * 4;
  int c0 = blockIdx.y * CGRP;
  int z = blockIdx.z;
  for (int i = t; i < CGRP * 9; i += 256) wl[i / 9][i % 9] = Wdw[c0 * 9 + i];
  const float* src = fmap + ((size_t)z * Cc + c0) * 4096;
#pragma unroll
  for (int it = 0; it < 12; ++it) {
    int idx = it * 256 + t;
    int c = idx / 96, rem = idx % 96, yy = rem >> 4, x4 = rem & 15;
    int gy = y0 - 1 + yy;
    F4 v;
    if ((unsigned)gy < 64u)
      v.v = *(const float4*)&src[(size_t)c * 4096 + gy * 64 + x4 * 4];
    else
      v.f[0] = v.f[1] = v.f[2] = v.f[3] = 0.f;
#pragma unroll
    for (int j = 0; j < 4; ++j) sin_[c][yy * 64 + x4 * 4 + j] = v.f[j];
  }
  __syncthreads();
  int c8 = (t & 3) * 8;
  int nl = t >> 2;
  size_t nbase = (size_t)z * 4096 + (size_t)y0 * 64;
#pragma unroll
  for (int it = 0; it < 4; ++it) {
    int n = it * 64 + nl;
    int y = n >> 6, x = n & 63;
    union { ushort u[8]; uint4 q; } fo, go;
#pragma unroll
    for (int cc = 0; cc < 8; ++cc) {
      int c = c8 + cc;
      fo.u[cc] = f2bf(sin_[c][(y + 1) * 64 + x]);
      float acc = 0.f;
#pragma unroll
      for (int dy = 0; dy < 3; ++dy) {
#pragma unroll
        for (int dx = 0; dx < 3; ++dx) {
          int xx = x + dx - 1;
          float pv = ((unsigned)xx < 64u) ? sin_[c][(y + dy) * 64 + xx] : 0.f;
          acc += pv * wl[c][dy * 3 + dx];
        }
      }
      go.u[cc] = f2bf(acc);
    }
    *(uint4*)&fmapT[(nbase + n) * Cc + c0 + c8] = fo.q;
    *(uint4*)&dwT[(nbase + n) * Cc + c0 + c8] = go.q;
  }
}

// ---------------- all three weights f32 -> bf16 in one launch ----------------
__global__ __launch_bounds__(256) void cvtb3_k(const float* __restrict__ Wq,
                                               const float* __restrict__ Wkv,
                                               const float* __restrict__ Wout,
                                               ushort* __restrict__ WqB,
                                               ushort* __restrict__ WkvB,
                                               ushort* __restrict__ WoutB) {
  int i = blockIdx.x * 256 + threadIdx.x;
  const float* s;
  ushort* d;
  int idx;
  if (i < 32768) { s = Wq; d = WqB; idx = i; }
  else if (i < 98304) { s = Wkv; d = WkvB; idx = i - 32768; }
  else { s = Wout; d = WoutB; idx = i - 98304; }
  F4 v; v.v = *(const float4*)&s[(size_t)idx * 4];
  union { ushort u[4]; uint2 q; } o;
#pragma unroll
  for (int j = 0; j < 4; ++j) o.u[j] = f2bf(v.f[j]);
  *(uint2*)&d[(size_t)idx * 4] = o.q;
}

// ------- kv GEMM: kv[ch][n] = Wkv[ch][k] . dwT[n][k]; exp() on k-half --------
__global__ __launch_bounds__(256) void kvgemm_k(const ushort* __restrict__ P,
                                                const ushort* __restrict__ Q,
                                                ushort* __restrict__ Y,
                                                long qz, long yz) {
  __shared__ __align__(16) char lds[16384];
  char* LP = lds;
  char* LQ = lds + 8192;
  int t = threadIdx.x, w = t >> 6, l = t & 63;
  int z = blockIdx.z;
  const ushort* Pz = P + (size_t)(blockIdx.y * 128) * 256;
  const ushort* Qz = Q + (size_t)z * qz + (size_t)(blockIdx.x * 128) * 256;
  f32x4 acc[4][4];
#pragma unroll
  for (int i = 0; i < 4; ++i)
#pragma unroll
    for (int j = 0; j < 4; ++j) acc[i][j] = (f32x4){0.f, 0.f, 0.f, 0.f};
  int wr = (w >> 1) * 64, wc = (w & 1) * 64;
  int rl = l & 15, kc = l >> 4;
  int srow = (l >> 2) & 15, scol = l & 3;

  for (int k0 = 0; k0 < 256; k0 += 32) {
    __syncthreads();
#pragma unroll
    for (int j = 0; j < 2; ++j) {
      int row = (w * 2 + j) * 16 + srow;
      int g = scol ^ (row & 3);
      int off = __builtin_amdgcn_readfirstlane((w * 2 + j) * 1024);
      gload16(LP + off, Pz + (size_t)row * 256 + k0 + g * 8);
      gload16(LQ + off, Qz + (size_t)row * 256 + k0 + g * 8);
    }
    asm volatile("s_waitcnt vmcnt(0)" ::: "memory");
    __syncthreads();
    bf16x8 a[4], b[4];
#pragma unroll
    for (int i = 0; i < 4; ++i) a[i] = fragread(LP, wr + i * 16 + rl, kc);
#pragma unroll
    for (int i = 0; i < 4; ++i) b[i] = fragread(LQ, wc + i * 16 + rl, kc);
#pragma unroll
    for (int i = 0; i < 4; ++i)
#pragma unroll
      for (int j = 0; j < 4; ++j)
        acc[i][j] = __builtin_amdgcn_mfma_f32_16x16x32_bf16(a[i], b[j], acc[i][j], 0, 0, 0);
  }
  int r0 = blockIdx.y * 128 + wr, c0 = blockIdx.x * 128 + wc;
  ushort* Yz = Y + (size_t)z * yz;
#pragma unroll
  for (int i = 0; i < 4; ++i) {
#pragma unroll
    for (int reg = 0; reg < 4; ++reg) {
      int r = r0 + i * 16 + kc * 4 + reg;
#pragma unroll
      for (int j = 0; j < 4; ++j) {
        int c = c0 + j * 16 + rl;
        float v = acc[i][j][reg];
        Yz[(size_t)r * 4096 + c] = f2bf(r < 512 ? __expf(v) : v);
      }
    }
  }
}

// ------- ctxT'[e][d] = sum_n v[e][n]*ek[d][n]; also s[d] = sum_n ek[d][n] -------
__global__ __launch_bounds__(256) void ctx_mfma(const ushort* __restrict__ kv,
                                                float* __restrict__ ctxf,
                                                float* __restrict__ sf) {
  __shared__ __align__(16) char lds[8192];
  int t = threadIdx.x, w = t >> 6, l = t & 63;
  int s = blockIdx.x;
  int h = blockIdx.y & 7, z = blockIdx.y >> 3;
  const ushort* kb = kv + ((size_t)z * 1024 + h * 64) * 4096;
  const ushort* vb = kv + ((size_t)z * 1024 + 512 + h * 64) * 4096;
  f32x4 acc[2][2];
  f32x4 accs[2];
#pragma unroll
  for (int i = 0; i < 2; ++i) {
    accs[i] = (f32x4){0.f, 0.f, 0.f, 0.f};
#pragma unroll
    for (int j = 0; j < 2; ++j) acc[i][j] = (f32x4){0.f, 0.f, 0.f, 0.f};
  }
  bf16x8 ones;
#pragma unroll
  for (int i = 0; i < 8; ++i) ones[i] = (short)0x3F80;
  int wr = (w >> 1) * 32, wc = (w & 1) * 32;
  int rl = l & 15, kc = l >> 4;
  int srow = (l >> 2) & 15, scol = l & 3;
  for (int it = 0; it < 32; ++it) {
    int k0 = s * 1024 + it * 32;
    __syncthreads();
    {
      int row = w * 16 + srow;
      int g = scol ^ (row & 3);
      int off = __builtin_amdgcn_readfirstlane(w * 1024);
      gload16(lds + off, vb + (size_t)row * 4096 + k0 + g * 8);
      gload16(lds + 4096 + off, kb + (size_t)row * 4096 + k0 + g * 8);
    }
    asm volatile("s_waitcnt vmcnt(0)" ::: "memory");
    __syncthreads();
    bf16x8 a[2], b[2];
#pragma unroll
    for (int i = 0; i < 2; ++i) a[i] = fragread(lds, wr + i * 16 + rl, kc);
#pragma unroll
    for (int i = 0; i < 2; ++i) b[i] = fragread(lds + 4096, wc + i * 16 + rl, kc);
#pragma unroll
    for (int i = 0; i < 2; ++i)
#pragma unroll
      for (int j = 0; j < 2; ++j)
        acc[i][j] = __builtin_amdgcn_mfma_f32_16x16x32_bf16(a[i], b[j], acc[i][j], 0, 0, 0);
    if (w < 2) {
#pragma unroll
      for (int j = 0; j < 2; ++j)
        accs[j] = __builtin_amdgcn_mfma_f32_16x16x32_bf16(b[j], ones, accs[j], 0, 0, 0);
    }
  }
  float* cf = ctxf + (size_t)(z * 8 + h) * 4096;
#pragma unroll
  for (int i = 0; i < 2; ++i)
#pragma unroll
    for (int reg = 0; reg < 4; ++reg) {
      int e = wr + i * 16 + kc * 4 + reg;
#pragma unroll
      for (int j = 0; j < 2; ++j) {
        int d = wc + j * 16 + rl;
        atomicAdd(&cf[e * 64 + d], acc[i][j][reg]);
      }
    }
  if (w < 2 && rl == 0) {
    float* sp = sf + (size_t)(z * 8 + h) * 64;
#pragma unroll
    for (int j = 0; j < 2; ++j)
#pragma unroll
      for (int reg = 0; reg < 4; ++reg)
        atomicAdd(&sp[wc + j * 16 + kc * 4 + reg], accs[j][reg]);
  }
}

// ------------- ctx normalize (1/s_d) + f32 -> swizzled bf16 pages -------------
__global__ __launch_bounds__(256) void ctx_cvt(const float* __restrict__ ctxf,
                                               const float* __restrict__ sf,
                                               ushort* __restrict__ cswz) {
  int page = blockIdx.x;
  const float* s = ctxf + (size_t)page * 4096;
  const float* sp = sf + (size_t)page * 64;
  char* d = (char*)(cswz + (size_t)page * 4096);
  int t = threadIdx.x;
  int e = t >> 2, d0 = (t & 3) * 16;
#pragma unroll
  for (int j = 0; j < 16; ++j) {
    int dd = d0 + j;
    int byte = e * 128 + (((dd >> 3) ^ (e & 7)) << 4) + (dd & 7) * 2;
    *(ushort*)(d + byte) = f2bf(s[e * 64 + dd] / sp[dd]);
  }
}

// ======== MEGA: q-GEMM -> q-softmax -> PV(ctx) -> GELU -> out-GEMM ========
// 64-row n-tiles, grid 64x8 = 512 blocks (2/CU). LDS 64KB:
//   qbuf 16KB [64 n][128 d], Bres 32KB resident fmapT [64 n][256 k], Asg 16KB.
__global__ __launch_bounds__(256, 2) void qao_k(const ushort* __restrict__ fmapT,
                                                const ushort* __restrict__ WqB,
                                                const ushort* __restrict__ cswz,
                                                const ushort* __restrict__ WoutB,
                                                const float* __restrict__ bout,
                                                float* __restrict__ out) {
  __shared__ __align__(16) char lds[65536];
  char* qbuf = lds;            // 16KB, rows 256B, XOR slot^(n&7)
  char* Bres = lds + 16384;    // 32KB, rows 512B, XOR slot^(n&7)
  char* Asg  = lds + 49152;    // 16KB staging (2x8KB Wq dbuf / ctx pages / Wout)
  int t = threadIdx.x, w = t >> 6, l = t & 63;
  int z = blockIdx.y, n0 = blockIdx.x * 64;
  int rl = l & 15, kc = l >> 4;
  int srow = (l >> 2) & 15, scol = l & 3;
  int wrd = (w >> 1) * 64;   // d offset within 128-chunk
  int wcn = (w & 1) * 32;    // n offset
  int hh = w >> 1;           // head within chunk pair

  const ushort* fT = fmapT + ((size_t)z * 4096 + n0) * 256;

  // ---- stage resident fmapT tile: 64 rows x 256 k, inverse-swizzled source
#pragma unroll
  for (int p = 0; p < 8; ++p) {
    int row = (w * 8 + p) * 2 + (l >> 5);
    int cs = l & 31;
    int off = __builtin_amdgcn_readfirstlane((w * 8 + p) * 1024);
    gload16(Bres + off, fT + (size_t)row * 256 + ((cs ^ (row & 7)) * 8));
  }

  f32x4 oacc[4][4];  // rows c = w*64+16i+4kc+reg, cols n = 16j+rl
#pragma unroll
  for (int i = 0; i < 4; ++i)
#pragma unroll
    for (int j = 0; j < 4; ++j) oacc[i][j] = (f32x4){0.f, 0.f, 0.f, 0.f};

  asm volatile("s_waitcnt vmcnt(0)" ::: "memory");
  __syncthreads();

  for (int c = 0; c < 4; ++c) {
    const ushort* Wqc = WqB + (size_t)(c * 128) * 256;
    // ---- q-GEMM chunk: Y[128 d][64 n], K=256, dbuf Wq staging
    f32x4 qa[4][2];
#pragma unroll
    for (int i = 0; i < 4; ++i)
#pragma unroll
      for (int j = 0; j < 2; ++j) qa[i][j] = (f32x4){0.f, 0.f, 0.f, 0.f};
    // prologue: stage step 0 into half 0
#pragma unroll
    for (int j = 0; j < 2; ++j) {
      int row = (w * 2 + j) * 16 + srow;
      int g = scol ^ (row & 3);
      int off = __builtin_amdgcn_readfirstlane((w * 2 + j) * 1024);
      gload16(Asg + off, Wqc + (size_t)row * 256 + g * 8);
    }
    asm volatile("s_waitcnt vmcnt(0)" ::: "memory");
    __syncthreads();
#pragma unroll
    for (int k0 = 0; k0 < 256; k0 += 32) {
      char* cur = Asg + (((k0 >> 5) & 1) ? 8192 : 0);
      if (k0 + 32 < 256) {
        char* nxt = Asg + (((k0 >> 5) & 1) ? 0 : 8192);
#pragma unroll
        for (int j = 0; j < 2; ++j) {
          int row = (w * 2 + j) * 16 + srow;
          int g = scol ^ (row & 3);
          int off = __builtin_amdgcn_readfirstlane((w * 2 + j) * 1024);
          gload16(nxt + off, Wqc + (size_t)row * 256 + (k0 + 32) + g * 8);
        }
      }
      bf16x8 a[4], b[2];
#pragma unroll
      for (int i = 0; i < 4; ++i) a[i] = fragread(cur, wrd + i * 16 + rl, kc);
      int g0 = k0 >> 3;
#pragma unroll
      for (int j = 0; j < 2; ++j) {
        int n = wcn + 16 * j + rl;
        b[j] = *(const bf16x8*)(Bres + n * 512 + (((g0 + kc) ^ (n & 7)) << 4));
      }
#pragma unroll
      for (int i = 0; i < 4; ++i)
#pragma unroll
        for (int j = 0; j < 2; ++j)
          qa[i][j] = __builtin_amdgcn_mfma_f32_16x16x32_bf16(a[i], b[j], qa[i][j], 0, 0, 0);
      asm volatile("s_waitcnt vmcnt(0)" ::: "memory");
      __syncthreads();
    }
    // ---- issue ctx page loads (2 heads, 16KB linear) to overlap softmax
    {
      const char* cp = (const char*)cswz + (size_t)(z * 8 + c * 2) * 8192;
#pragma unroll
      for (int r = 0; r < 4; ++r) {
        int off = __builtin_amdgcn_readfirstlane(w * 4096 + r * 1024);
        gload16(Asg + off, cp + off + l * 16);
      }
    }
    // ---- softmax over d (this wave's head = 64 rows) per column
#pragma unroll
    for (int j = 0; j < 2; ++j) {
      float m = -1e30f;
#pragma unroll
      for (int i = 0; i < 4; ++i)
#pragma unroll
        for (int r = 0; r < 4; ++r) m = fmaxf(m, qa[i][j][r]);
      m = fmaxf(m, __shfl_xor(m, 16, 64));
      m = fmaxf(m, __shfl_xor(m, 32, 64));
      float s = 0.f;
#pragma unroll
      for (int i = 0; i < 4; ++i)
#pragma unroll
        for (int r = 0; r < 4; ++r) {
          float e = __expf(qa[i][j][r] - m);
          qa[i][j][r] = e;
          s += e;
        }
      s += __shfl_xor(s, 16, 64);
      s += __shfl_xor(s, 32, 64);
      float inv = 0.125f / s;
#pragma unroll
      for (int i = 0; i < 4; ++i)
#pragma unroll
        for (int r = 0; r < 4; ++r) qa[i][j][r] *= inv;
    }
    // ---- write q to qbuf [n][d] (b64 packed, swizzled)
#pragma unroll
    for (int i = 0; i < 4; ++i)
#pragma unroll
      for (int j = 0; j < 2; ++j) {
        int n = wcn + 16 * j + rl;
        int dby = (wrd + 16 * i + 4 * kc) * 2;
        union { ushort u[4]; unsigned long long q; } pk;
#pragma unroll
        for (int r = 0; r < 4; ++r) pk.u[r] = f2bf(qa[i][j][r]);
        *(unsigned long long*)(qbuf + n * 256 + (dby ^ ((n & 7) << 4))) = pk.q;
      }
    asm volatile("s_waitcnt vmcnt(0)" ::: "memory");
    __syncthreads();
    // ---- PV: Y[e 64][n 32] per wave (head hh), K=64
    f32x4 pacc[4][2];
#pragma unroll
    for (int i = 0; i < 4; ++i)
#pragma unroll
      for (int j = 0; j < 2; ++j) pacc[i][j] = (f32x4){0.f, 0.f, 0.f, 0.f};
    const char* ctxpg = Asg + hh * 8192;
#pragma unroll
    for (int s = 0; s < 2; ++s) {
      bf16x8 a[4], b[2];
#pragma unroll
      for (int i = 0; i < 4; ++i) {
        int e = 16 * i + rl;
        a[i] = *(const bf16x8*)(ctxpg + e * 128 + (((s * 4 + kc) ^ (e & 7)) << 4));
      }
#pragma unroll
      for (int j = 0; j < 2; ++j) {
        int n = wcn + 16 * j + rl;
        int dby = hh * 128 + s * 64 + kc * 16;
        b[j] = *(const bf16x8*)(qbuf + n * 256 + (dby ^ ((n & 7) << 4)));
      }
#pragma unroll
      for (int i = 0; i < 4; ++i)
#pragma unroll
        for (int j = 0; j < 2; ++j)
          pacc[i][j] = __builtin_amdgcn_mfma_f32_16x16x32_bf16(a[i], b[j], pacc[i][j], 0, 0, 0);
    }
    __syncthreads();  // qbuf reads done before GELU overwrite
    // ---- GELU -> gout into qbuf [n][m-local 128]
#pragma unroll
    for (int i = 0; i < 4; ++i)
#pragma unroll
      for (int j = 0; j < 2; ++j) {
        int n = wcn + 16 * j + rl;
        int mby = (hh * 64 + 16 * i + 4 * kc) * 2;
        union { ushort u[4]; unsigned long long q; } pk;
#pragma unroll
        for (int r = 0; r < 4; ++r) pk.u[r] = f2bf(gelu_exact(pacc[i][j][r]));
        *(unsigned long long*)(qbuf + n * 256 + (mby ^ ((n & 7) << 4))) = pk.q;
      }
    __syncthreads();
    // ---- out-GEMM partial: oacc[256 c][64 n] += Wout[:, c*128..] . gout^T
#pragma unroll
    for (int ks = 0; ks < 4; ++ks) {
      if (ks) __syncthreads();
#pragma unroll
      for (int jj = 0; jj < 4; ++jj) {
        int row = w * 64 + jj * 16 + srow;
        int g = scol ^ (row & 3);
        int off = __builtin_amdgcn_readfirstlane((w * 4 + jj) * 1024);
        gload16(Asg + off, WoutB + (size_t)row * 512 + c * 128 + ks * 32 + g * 8);
      }
      asm volatile("s_waitcnt vmcnt(0)" ::: "memory");
      __syncthreads();
      bf16x8 a[4], b[4];
#pragma unroll
      for (int i = 0; i < 4; ++i) a[i] = fragread(Asg, w * 64 + 16 * i + rl, kc);
#pragma unroll
      for (int j = 0; j < 4; ++j) {
        int n = 16 * j + rl;
        b[j] = *(const bf16x8*)(qbuf + n * 256 + ((ks * 64 + kc * 16) ^ ((n & 7) << 4)));
      }
#pragma unroll
      for (int i = 0; i < 4; ++i)
#pragma unroll
        for (int j = 0; j < 4; ++j)
          oacc[i][j] = __builtin_amdgcn_mfma_f32_16x16x32_bf16(a[i], b[j], oacc[i][j], 0, 0, 0);
    }
    __syncthreads();  // Asg/qbuf free for next chunk
  }
  // ---- epilogue: bias + f32 store
  float* oz = out + (size_t)z * Cc * Nn + n0;
#pragma unroll
  for (int i = 0; i < 4; ++i) {
#pragma unroll
    for (int r = 0; r < 4; ++r) {
      int crow = w * 64 + 16 * i + 4 * kc + r;
      float bv = bout[crow];
      float* rowp = oz + (size_t)crow * 4096;
#pragma unroll
      for (int j = 0; j < 4; ++j) rowp[16 * j + rl] = oacc[i][j][r] + bv;
    }
  }
}

extern "C" void kernel_launch(void* const* d_in, const int* in_sizes, int n_in,
                              void* d_out, int out_size, void* d_ws, size_t ws_size,
                              hipStream_t stream) {
  (void)in_sizes; (void)n_in; (void)out_size; (void)ws_size;
  const float* fmap = (const float*)d_in[0];
  const float* Wq   = (const float*)d_in[1];
  const float* Wdw  = (const float*)d_in[2];
  const float* Wkv  = (const float*)d_in[3];
  const float* Wout = (const float*)d_in[4];
  const float* bout = (const float*)d_in[5];
  float* out = (float*)d_out;

  ushort* WqB   = (ushort*)d_ws;
  ushort* WkvB  = WqB + 512 * 256;
  ushort* WoutB = WkvB + 1024 * 256;
  ushort* fmapT = WoutB + 256 * 512;
  ushort* dwT   = fmapT + (size_t)Bx * 4096 * 256;
  ushort* kv    = dwT + (size_t)Bx * 4096 * 256;
  ushort* cswz  = kv + (size_t)Bx * 1024 * 4096;
  float*  ctxf  = (float*)(cswz + (size_t)Bx * 8 * 4096);
  float*  sf    = ctxf + (size_t)Bx * 8 * 64 * 64;

  cvtb3_k<<<dim3(512), 256, 0, stream>>>(Wq, Wkv, Wout, WqB, WkvB, WoutB);
  convfuse_k<<<dim3(16, Cc / CGRP, Bx), 256, 0, stream>>>(fmap, Wdw, fmapT, dwT);
  kvgemm_k<<<dim3(32, 8, Bx), 256, 0, stream>>>(
      WkvB, dwT, kv, (long)4096 * 256, (long)1024 * 4096);
  hipMemsetAsync(ctxf, 0, (size_t)Bx * 8 * (4096 + 64) * sizeof(float), stream);
  ctx_mfma<<<dim3(4, Bx * 8), 256, 0, stream>>>(kv, ctxf, sf);
  ctx_cvt<<<dim3(Bx * 8), 256, 0, stream>>>(ctxf, sf, cswz);
  qao_k<<<dim3(64, Bx), 256, 0, stream>>>(fmapT, WqB, cswz, WoutB, bout, out);
}